// Round 14
// baseline (3129.785 us; speedup 1.0000x reference)
//
#include <hip/hip_runtime.h>

#define STEPS 6

typedef __attribute__((ext_vector_type(8))) short short8;
typedef __attribute__((ext_vector_type(4))) float f32x4;
typedef __attribute__((ext_vector_type(8))) float f32x8;
typedef __attribute__((ext_vector_type(2))) float f32x2e;

__device__ __forceinline__ float bf2f(unsigned int u16) {
    union { unsigned int u; float f; } v; v.u = u16 << 16; return v.f;
}
__device__ __forceinline__ unsigned int f2bf(float x) {
    union { float f; unsigned int u; } v; v.f = x;
    unsigned int r = v.u + 0x7fffu + ((v.u >> 16) & 1u);
    return r >> 16;
}
__device__ __forceinline__ void decompv(const f32x8& v, short8& hi, short8& lo) {
#pragma unroll
    for (int j = 0; j < 8; ++j) {
        float x = v[j];
        unsigned int h = f2bf(x);
        hi[j] = (short)h;
        lo[j] = (short)f2bf(x - bf2f(h));
    }
}
// async global->LDS, 16B per lane: LDS dst = uniform base + lane*16
__device__ __forceinline__ void gl_lds16(const void* g, void* s) {
    __builtin_amdgcn_global_load_lds(
        (const __attribute__((address_space(1))) unsigned int*)g,
        (__attribute__((address_space(3))) unsigned int*)s, 16, 0, 0);
}

// ---------------- CSR build ----------------
__global__ __launch_bounds__(256) void hist_k(const int* __restrict__ dst, int* __restrict__ deg, int E) {
    int e = blockIdx.x * 256 + threadIdx.x;
    if (e < E) atomicAdd(&deg[dst[e]], 1);
}

__global__ __launch_bounds__(256) void scan1_k(const int* __restrict__ in, int* __restrict__ ex,
                                               int* __restrict__ bs, int N) {
    __shared__ int sd[256];
    int t = threadIdx.x;
    int base = blockIdx.x * 1024 + t * 4;
    int v[4]; int s = 0;
#pragma unroll
    for (int i = 0; i < 4; ++i) { int idx = base + i; v[i] = idx < N ? in[idx] : 0; s += v[i]; }
    sd[t] = s; __syncthreads();
    for (int o = 1; o < 256; o <<= 1) {
        int x = (t >= o) ? sd[t - o] : 0;
        __syncthreads();
        sd[t] += x;
        __syncthreads();
    }
    int run = sd[t] - s;
#pragma unroll
    for (int i = 0; i < 4; ++i) { int idx = base + i; if (idx < N) ex[idx] = run; run += v[i]; }
    if (t == 255) bs[blockIdx.x] = sd[255];
}

__global__ __launch_bounds__(1024) void scan2_k(const int* __restrict__ bs, int* __restrict__ be, int nb) {
    __shared__ int sd[1024];
    int t = threadIdx.x;
    int v = (t < nb) ? bs[t] : 0;
    sd[t] = v; __syncthreads();
    for (int o = 1; o < 1024; o <<= 1) {
        int x = (t >= o) ? sd[t - o] : 0;
        __syncthreads();
        sd[t] += x;
        __syncthreads();
    }
    if (t < nb) be[t] = sd[t] - v;
}

__global__ __launch_bounds__(256) void scan3_k(const int* __restrict__ ex, const int* __restrict__ be,
                                               int* __restrict__ offs, int N, int E) {
    int i = blockIdx.x * 256 + threadIdx.x;
    if (i < N) offs[i] = ex[i] + be[i >> 10];
    if (i == N) offs[N] = E;
}

__global__ __launch_bounds__(256) void scatter_k(const int* __restrict__ src, const int* __restrict__ dst,
                                                 const int* __restrict__ offs,
                                                 int* __restrict__ cursor, int* __restrict__ src_sorted,
                                                 int* __restrict__ eid_sorted, int E) {
    int e = blockIdx.x * 256 + threadIdx.x;
    if (e >= E) return;
    int d = dst[e];
    int pos = offs[d] + atomicAdd(&cursor[d], 1);
    src_sorted[pos] = src[e];
    eid_sorted[pos] = e;
}

// ---------------- weight packing: hi+lo bf16 planes, B-fragment order ----------------
// frag addr: ((ct*KS + ks)*64 + lane)*8 + j ; k = ks*32 + (lane>>4)*8 + j, col = ct*16 + (lane&15)
// per-step (stride 294912 elems): hi plane at +0, lo plane at +147456
// mat offsets (elems): W1:0 (32768), W2:32768 (16384), Wz:49152, Wr:81920, Wh:114688
__global__ __launch_bounds__(256) void pack_k(const float* __restrict__ W_m1, const float* __restrict__ W_m2,
                                              const float* __restrict__ W_z, const float* __restrict__ W_r,
                                              const float* __restrict__ W_h, unsigned short* __restrict__ packed) {
    const int s = blockIdx.y, mat = blockIdx.z;
    const int t = blockIdx.x * 256 + threadIdx.x;
    const int lane = t & 63;
    int KS, width; size_t moff;
    if (mat == 0)      { KS = 4; width = 256; moff = 0; }
    else if (mat == 1) { KS = 4; width = 128; moff = 32768; }
    else if (mat == 2) { KS = 8; width = 128; moff = 49152; }
    else if (mat == 3) { KS = 8; width = 128; moff = 81920; }
    else               { KS = 8; width = 128; moff = 114688; }
    const int total = (width >> 4) * KS * 64;
    if (t >= total) return;
    const int ks = (t >> 6) % KS;
    const int ct = (t >> 6) / KS;
    const int col = ct * 16 + (lane & 15);
    const int kb = ks * 32 + (lane >> 4) * 8;
    unsigned short* dh = packed + (size_t)s * 294912 + moff;
    unsigned short* dl = dh + 147456;
#pragma unroll
    for (int j = 0; j < 8; ++j) {
        const int k = kb + j;
        float v;
        if (mat == 0) {
            const float* W = W_m1 + (size_t)s * 260 * 128;
            v = (col < 128) ? W[k * 128 + col] : W[(128 + k) * 128 + (col - 128)];
        } else if (mat == 1) {
            v = W_m2[(size_t)s * 16384 + k * 128 + col];
        } else if (mat == 2) {
            v = W_z[(size_t)s * 32768 + k * 128 + col];
        } else if (mat == 3) {
            v = W_r[(size_t)s * 32768 + k * 128 + col];
        } else {
            v = W_h[(size_t)s * 32768 + k * 128 + col];
        }
        unsigned int hb = f2bf(v);
        dh[(size_t)t * 8 + j] = (unsigned short)hb;
        dl[(size_t)t * 8 + j] = (unsigned short)f2bf(v - bf2f(hb));
    }
}

// ---------------- head weight packing: [Wc1|Wp1] as 128x128, hi+lo (16384 elems each) ----------------
__global__ __launch_bounds__(256) void pack_head_k(const float* __restrict__ Wc1,
                                                   const float* __restrict__ Wp1,
                                                   unsigned short* __restrict__ dst) {
    const int t = blockIdx.x * 256 + threadIdx.x;   // 0..2047
    if (t >= 2048) return;
    const int lane = t & 63;
    const int ks = (t >> 6) & 3;
    const int ct = (t >> 6) >> 2;
    const int col = ct * 16 + (lane & 15);
    const int kb = ks * 32 + (lane >> 4) * 8;
    unsigned short* dh = dst;
    unsigned short* dl = dst + 16384;
#pragma unroll
    for (int j = 0; j < 8; ++j) {
        const int k = kb + j;
        float v = (col < 64) ? Wc1[k * 64 + col] : Wp1[k * 64 + (col - 64)];
        unsigned int hb = f2bf(v);
        dh[(size_t)t * 8 + j] = (unsigned short)hb;
        dl[(size_t)t * 8 + j] = (unsigned short)f2bf(v - bf2f(hb));
    }
}

// ---------------- input projection -> f32 h ----------------
__global__ __launch_bounds__(256) void proj_k(const float* __restrict__ nf, const float* __restrict__ Win,
                                              const float* __restrict__ bin,
                                              float* __restrict__ hf, int N) {
    const int lane = threadIdx.x & 63, wave = threadIdx.x >> 6;
    const int i = blockIdx.x * 4 + wave;
    if (i >= N) return;
    const int c0 = lane * 2;
    float a0 = bin[c0], a1 = bin[c0 + 1];
#pragma unroll
    for (int q = 0; q < 8; ++q) {
        float x = nf[(size_t)i * 8 + q];
        a0 += x * Win[q * 128 + c0];
        a1 += x * Win[q * 128 + c0 + 1];
    }
    hf[(size_t)i * 128 + c0] = a0;
    hf[(size_t)i * 128 + c0 + 1] = a1;
}

// ---------------- f32-accurate MFMA GEMM, direct L2 weight reads, no barriers ----------------
// MODE 0: [Xs|Xd] = h@[W1s|W1d] : A=hf lda=128; cgrp0 -> Xs bf16 [N,128]; cgrp1 -> Xd f32 X[:,128:256]
// MODE 1: agg = T@W2 + deg*b : A=X+128 lda=256, out f32 X[:,0:128]
template <int MODE>
__global__ __launch_bounds__(256, 4) void gemm_k(const float* __restrict__ A, int lda,
                                                 const unsigned short* __restrict__ pkh,
                                                 const unsigned short* __restrict__ pkl,
                                                 const float* __restrict__ bias,
                                                 const int* __restrict__ deg,
                                                 float* __restrict__ out, int ldo,
                                                 unsigned short* __restrict__ out_b,
                                                 int Nrows) {
    const int lane = threadIdx.x & 63;
    const int wave = threadIdx.x >> 6;
    const int l15 = lane & 15, l16 = lane >> 4;
    const int mrow = blockIdx.x * 64 + wave * 16;
    const int cgrp = blockIdx.y;

    int r0 = mrow + l15; if (r0 >= Nrows) r0 = 0;
    const float* ap = A + (size_t)r0 * lda;

    f32x4 acc[8];
#pragma unroll
    for (int ct = 0; ct < 8; ++ct) acc[ct] = (f32x4){0.f, 0.f, 0.f, 0.f};

    for (int ks = 0; ks < 4; ++ks) {
        const f32x8 av = *(const f32x8*)(ap + ks * 32 + l16 * 8);
        short8 ahi, alo;
        decompv(av, ahi, alo);
#pragma unroll
        for (int ct = 0; ct < 8; ++ct) {
            const size_t fb = (((size_t)(cgrp * 8 + ct) * 4 + ks) << 10) + lane * 16;
            const short8 wh = *(const short8*)((const char*)pkh + fb);
            const short8 wl = *(const short8*)((const char*)pkl + fb);
            acc[ct] = __builtin_amdgcn_mfma_f32_16x16x32_bf16(ahi, wh, acc[ct], 0, 0, 0);
            acc[ct] = __builtin_amdgcn_mfma_f32_16x16x32_bf16(alo, wh, acc[ct], 0, 0, 0);
            acc[ct] = __builtin_amdgcn_mfma_f32_16x16x32_bf16(ahi, wl, acc[ct], 0, 0, 0);
        }
    }
#pragma unroll
    for (int ct = 0; ct < 8; ++ct) {
        const int col = cgrp * 128 + ct * 16 + l15;
#pragma unroll
        for (int r = 0; r < 4; ++r) {
            const int row = mrow + l16 * 4 + r;
            if (row >= Nrows) continue;
            float v = acc[ct][r];
            if (MODE == 0) {
                if (cgrp == 0) out_b[(size_t)row * 128 + col] = (unsigned short)f2bf(v);
                else           out[(size_t)row * ldo + col] = v;   // col in 128..255 -> Xd slot
            } else {
                v += bias[col] * (float)deg[row];
                out[(size_t)row * ldo + col] = v;
            }
        }
    }
}

// ---------------- fused z,r,rh,hn,blend,LN — 512 thr: 4 rowgrp x 2 colgrp, 16 rows x 64 cols/wave ----------------
__global__ __launch_bounds__(512, 4) void zrh_k(float* __restrict__ hf,
                                                const float* __restrict__ X,  // [N,256]: 0:128 agg
                                                const unsigned short* __restrict__ pzh, const unsigned short* __restrict__ pzl,
                                                const unsigned short* __restrict__ prh, const unsigned short* __restrict__ prl,
                                                const unsigned short* __restrict__ phh, const unsigned short* __restrict__ phl,
                                                const float* __restrict__ bz, const float* __restrict__ br,
                                                const float* __restrict__ bh,
                                                const float* __restrict__ lns, const float* __restrict__ lnb,
                                                int N) {
    __shared__ char stg[49152];   // phase1: 48 weight lines x 1KB; phase2+: rhs[4][2112] f32 + LN partials
    float* rhs = reinterpret_cast<float*>(stg);
    float* lnp = reinterpret_cast<float*>(stg + 33792);  // [4][2][16][2]
    const int lane = threadIdx.x & 63;
    const int wave = threadIdx.x >> 6;           // 0..7
    const int rowgrp = wave >> 1, colgrp = wave & 1;
    const int l15 = lane & 15, l16 = lane >> 4;
    const int mrow = blockIdx.x * 64 + rowgrp * 16;

    int r0 = mrow + l15; if (r0 >= N) r0 = 0;

    f32x4 zac[4], rac[4], hac[4];
#pragma unroll
    for (int c = 0; c < 4; ++c) {
        zac[c] = (f32x4){0.f, 0.f, 0.f, 0.f};
        rac[c] = (f32x4){0.f, 0.f, 0.f, 0.f};
        hac[c] = (f32x4){0.f, 0.f, 0.f, 0.f};
    }

    const unsigned short* wsrc[6] = {pzh, pzl, prh, prl, phh, phl};

    // ---- phase 1: staged weights, counted vmcnt, 2 barriers/ks ----
    f32x8 acur = *(const f32x8*)(hf + (size_t)r0 * 128 + l16 * 8);
    for (int ks = 0; ks < 8; ++ks) {
        const int nplanes = (ks >= 4) ? 6 : 4;
        for (int i = 0; i < nplanes; ++i)
            gl_lds16((const char*)wsrc[i] + (((size_t)(wave * 8 + ks)) << 10) + lane * 16,
                     &stg[(i * 8 + wave) << 10]);
        f32x8 anext;
        if (ks < 7) {
            const int kn = (ks + 1) * 32 + l16 * 8;
            const float* ap = (kn < 128) ? (hf + (size_t)r0 * 128 + kn)
                                         : (X + (size_t)r0 * 256 + (kn - 128));
            f32x4 pa = *(const f32x4*)ap;
            f32x4 pb = *(const f32x4*)(ap + 4);
            anext[0] = pa[0]; anext[1] = pa[1]; anext[2] = pa[2]; anext[3] = pa[3];
            anext[4] = pb[0]; anext[5] = pb[1]; anext[6] = pb[2]; anext[7] = pb[3];
        }
        short8 ahi, alo;
        decompv(acur, ahi, alo);
        if (ks < 7) asm volatile("s_waitcnt vmcnt(2)" ::: "memory");
        else        asm volatile("s_waitcnt vmcnt(0)" ::: "memory");
        __builtin_amdgcn_sched_barrier(0);
        __builtin_amdgcn_s_barrier();
        __builtin_amdgcn_sched_barrier(0);
#pragma unroll
        for (int c = 0; c < 4; ++c) {
            const int ct = colgrp * 4 + c;
            const short8 wzh = *(const short8*)(stg + ((0 * 8 + ct) << 10) + lane * 16);
            const short8 wzl = *(const short8*)(stg + ((1 * 8 + ct) << 10) + lane * 16);
            const short8 wrh = *(const short8*)(stg + ((2 * 8 + ct) << 10) + lane * 16);
            const short8 wrl = *(const short8*)(stg + ((3 * 8 + ct) << 10) + lane * 16);
            zac[c] = __builtin_amdgcn_mfma_f32_16x16x32_bf16(ahi, wzh, zac[c], 0, 0, 0);
            zac[c] = __builtin_amdgcn_mfma_f32_16x16x32_bf16(alo, wzh, zac[c], 0, 0, 0);
            zac[c] = __builtin_amdgcn_mfma_f32_16x16x32_bf16(ahi, wzl, zac[c], 0, 0, 0);
            rac[c] = __builtin_amdgcn_mfma_f32_16x16x32_bf16(ahi, wrh, rac[c], 0, 0, 0);
            rac[c] = __builtin_amdgcn_mfma_f32_16x16x32_bf16(alo, wrh, rac[c], 0, 0, 0);
            rac[c] = __builtin_amdgcn_mfma_f32_16x16x32_bf16(ahi, wrl, rac[c], 0, 0, 0);
            if (ks >= 4) {
                const short8 wbh = *(const short8*)(stg + ((4 * 8 + ct) << 10) + lane * 16);
                const short8 wbl = *(const short8*)(stg + ((5 * 8 + ct) << 10) + lane * 16);
                hac[c] = __builtin_amdgcn_mfma_f32_16x16x32_bf16(ahi, wbh, hac[c], 0, 0, 0);
                hac[c] = __builtin_amdgcn_mfma_f32_16x16x32_bf16(alo, wbh, hac[c], 0, 0, 0);
                hac[c] = __builtin_amdgcn_mfma_f32_16x16x32_bf16(ahi, wbl, hac[c], 0, 0, 0);
            }
        }
        __builtin_amdgcn_sched_barrier(0);
        __builtin_amdgcn_s_barrier();
        acur = anext;
    }

    // ---- phase 2: z = sigmoid (keep); rh = sigmoid(r)*h -> LDS rhs[rowgrp][rowl][col] ----
#pragma unroll
    for (int c = 0; c < 4; ++c) {
        const int col = (colgrp * 4 + c) * 16 + l15;
#pragma unroll
        for (int r = 0; r < 4; ++r) {
            const int rowl = l16 * 4 + r;
            const int row = mrow + rowl;
            const size_t idx = (size_t)(row < N ? row : 0) * 128 + col;
            float zp = zac[c][r] + bz[col];
            zac[c][r] = 1.f / (1.f + expf(-zp));
            float rp = rac[c][r] + br[col];
            float rr = 1.f / (1.f + expf(-rp));
            rhs[rowgrp * 2112 + rowl * 132 + col] = rr * hf[idx];
        }
    }
    __syncthreads();

    // ---- phase 3: hn += rh @ Wh_top (K=128), weights direct from L2 ----
    for (int ks = 0; ks < 4; ++ks) {
        const f32x8 v = *(const f32x8*)(rhs + rowgrp * 2112 + l15 * 132 + (ks * 4 + l16) * 8);
        short8 ahi, alo;
        decompv(v, ahi, alo);
#pragma unroll
        for (int c = 0; c < 4; ++c) {
            const int ct = colgrp * 4 + c;
            const size_t fb = (((size_t)(ct * 8 + ks)) << 10) + lane * 16;
            const short8 wh = *(const short8*)((const char*)phh + fb);
            const short8 wl = *(const short8*)((const char*)phl + fb);
            hac[c] = __builtin_amdgcn_mfma_f32_16x16x32_bf16(ahi, wh, hac[c], 0, 0, 0);
            hac[c] = __builtin_amdgcn_mfma_f32_16x16x32_bf16(alo, wh, hac[c], 0, 0, 0);
            hac[c] = __builtin_amdgcn_mfma_f32_16x16x32_bf16(ahi, wl, hac[c], 0, 0, 0);
        }
    }

    // ---- phase 4: blend + cross-wave LayerNorm -> hf ----
#pragma unroll
    for (int c = 0; c < 4; ++c) {
        const int col = (colgrp * 4 + c) * 16 + l15;
#pragma unroll
        for (int r = 0; r < 4; ++r) {
            const int row = mrow + l16 * 4 + r;
            const size_t idx = (size_t)(row < N ? row : 0) * 128 + col;
            float hn = tanhf(hac[c][r] + bh[col]);
            float zz = zac[c][r];
            hac[c][r] = (1.f - zz) * hf[idx] + zz * hn;
        }
    }
    float sr[4], ssr[4];
#pragma unroll
    for (int r = 0; r < 4; ++r) {
        float s = 0.f, ss = 0.f;
#pragma unroll
        for (int c = 0; c < 4; ++c) {
            float y = hac[c][r];
            s += y; ss += y * y;
        }
#pragma unroll
        for (int m = 1; m < 16; m <<= 1) {
            s += __shfl_xor(s, m, 64);
            ss += __shfl_xor(ss, m, 64);
        }
        sr[r] = s; ssr[r] = ss;
        if (l15 == 0) {
            float* p = lnp + (((rowgrp * 2 + colgrp) * 16) + (l16 * 4 + r)) * 2;
            p[0] = s; p[1] = ss;
        }
    }
    __syncthreads();
#pragma unroll
    for (int r = 0; r < 4; ++r) {
        const int rowl = l16 * 4 + r;
        const int row = mrow + rowl;
        const float* po = lnp + (((rowgrp * 2 + (colgrp ^ 1)) * 16) + rowl) * 2;
        float s = sr[r] + po[0];
        float ss = ssr[r] + po[1];
        float mean = s * (1.f / 128.f);
        float var = ss * (1.f / 128.f) - mean * mean;
        float inv = rsqrtf(var + 1e-6f);
        if (row < N) {
#pragma unroll
            for (int c = 0; c < 4; ++c) {
                const int col = (colgrp * 4 + c) * 16 + l15;
                hf[(size_t)row * 128 + col] = (hac[c][r] - mean) * inv * lns[col] + lnb[col];
            }
        }
    }
}

// ---------------- edge accumulate: T[v] = sum relu(Xs16[src]+Xd[v]+ef@Wef+b1) -> X[:,128:256] (f32) ----
__global__ __launch_bounds__(256) void edge_k(float* __restrict__ X,
                                              const unsigned short* __restrict__ Xs16,
                                              const int* __restrict__ offs,
                                              const int* __restrict__ src_sorted,
                                              const int* __restrict__ eid_sorted,
                                              const float* __restrict__ ef_all,
                                              const float* __restrict__ Wm1_s,
                                              const float* __restrict__ bm1_s,
                                              int N) {
    const int lane = threadIdx.x & 63, wave = threadIdx.x >> 6;
    const int v = blockIdx.x * 4 + wave;
    if (v >= N) return;
    const int c0 = lane * 2;
    const f32x2e xd = __builtin_nontemporal_load(
        reinterpret_cast<const f32x2e*>(X + (size_t)v * 256 + 128 + c0));
    const float base0 = xd[0] + bm1_s[c0];
    const float base1 = xd[1] + bm1_s[c0 + 1];
    const float w0x = Wm1_s[256 * 128 + c0], w0y = Wm1_s[256 * 128 + c0 + 1];
    const float w1x = Wm1_s[257 * 128 + c0], w1y = Wm1_s[257 * 128 + c0 + 1];
    const float w2x = Wm1_s[258 * 128 + c0], w2y = Wm1_s[258 * 128 + c0 + 1];
    const float w3x = Wm1_s[259 * 128 + c0], w3y = Wm1_s[259 * 128 + c0 + 1];
    float acc0 = 0.f, acc1 = 0.f;
    const int beg = offs[v], end = offs[v + 1];
    for (int i = beg; i < end; ++i) {
        int sn = __builtin_nontemporal_load(src_sorted + i);
        int eid = __builtin_nontemporal_load(eid_sorted + i);
        f32x4 ef = __builtin_nontemporal_load(reinterpret_cast<const f32x4*>(ef_all) + eid);
        unsigned int xs = *reinterpret_cast<const unsigned int*>(Xs16 + (size_t)sn * 128 + c0);
        float e0 = ef[0] * w0x + ef[1] * w1x + ef[2] * w2x + ef[3] * w3x;
        float e1 = ef[0] * w0y + ef[1] * w1y + ef[2] * w2y + ef[3] * w3y;
        acc0 += fmaxf(bf2f(xs & 0xffffu) + base0 + e0, 0.f);
        acc1 += fmaxf(bf2f(xs >> 16) + base1 + e1, 0.f);
    }
    X[(size_t)v * 256 + 128 + c0] = acc0;   // T overwrites Xd (consumed above)
    X[(size_t)v * 256 + 129 + c0] = acc1;
}

// ---------------- heads: MFMA stage-1 (h@[Wc1|Wp1]) + LDS stage-2 ----------------
__global__ __launch_bounds__(256, 4) void head_k(const float* __restrict__ hf,
                                                 const unsigned short* __restrict__ pH,  // hi; lo at +16384
                                                 const float* __restrict__ bc1, const float* __restrict__ bp1,
                                                 const float* __restrict__ Wc2, const float* __restrict__ bc2,
                                                 const float* __restrict__ Wp2, const float* __restrict__ bp2,
                                                 float* __restrict__ out, int N) {
    __shared__ float tls[4][16][132];
    const int lane = threadIdx.x & 63, wave = threadIdx.x >> 6;
    const int l15 = lane & 15, l16 = lane >> 4;
    const int mrow = blockIdx.x * 64 + wave * 16;
    const unsigned short* pHl = pH + 16384;

    int r0 = mrow + l15; if (r0 >= N) r0 = 0;
    const float* ap = hf + (size_t)r0 * 128;

    f32x4 acc[8];
#pragma unroll
    for (int ct = 0; ct < 8; ++ct) acc[ct] = (f32x4){0.f, 0.f, 0.f, 0.f};

    for (int ks = 0; ks < 4; ++ks) {
        const f32x8 av = *(const f32x8*)(ap + ks * 32 + l16 * 8);
        short8 ahi, alo;
        decompv(av, ahi, alo);
#pragma unroll
        for (int ct = 0; ct < 8; ++ct) {
            const size_t fb = (((size_t)(ct * 4 + ks)) << 10) + lane * 16;
            const short8 wh = *(const short8*)((const char*)pH + fb);
            const short8 wl = *(const short8*)((const char*)pHl + fb);
            acc[ct] = __builtin_amdgcn_mfma_f32_16x16x32_bf16(ahi, wh, acc[ct], 0, 0, 0);
            acc[ct] = __builtin_amdgcn_mfma_f32_16x16x32_bf16(alo, wh, acc[ct], 0, 0, 0);
            acc[ct] = __builtin_amdgcn_mfma_f32_16x16x32_bf16(ahi, wl, acc[ct], 0, 0, 0);
        }
    }
    // relu + bias -> per-wave LDS tile (cols 0:64 = cls-hidden, 64:128 = prob-hidden)
#pragma unroll
    for (int ct = 0; ct < 8; ++ct) {
        const int col = ct * 16 + l15;
        const float b = (col < 64) ? bc1[col] : bp1[col - 64];
#pragma unroll
        for (int r = 0; r < 4; ++r) {
            const int rowl = l16 * 4 + r;
            tls[wave][rowl][col] = fmaxf(acc[ct][r] + b, 0.f);
        }
    }
    // stage 2: 4-lane groups per row
    const int rowl = lane & 15;
    const int g = lane >> 4;
    const int row = mrow + rowl;
    const float* tr = &tls[wave][rowl][0];
    float o0 = 0.f, o1 = 0.f;
    if (g == 0) {
        for (int k = 0; k < 64; ++k) { float tv = tr[k]; o0 += tv * Wc2[k * 5 + 0]; o1 += tv * Wc2[k * 5 + 4]; }
    } else if (g == 1) {
        for (int k = 0; k < 64; ++k) { o0 += tr[k] * Wc2[k * 5 + 1]; o1 += tr[64 + k] * Wp2[k]; }
    } else if (g == 2) {
        for (int k = 0; k < 64; ++k) o0 += tr[k] * Wc2[k * 5 + 2];
    } else {
        for (int k = 0; k < 64; ++k) o0 += tr[k] * Wc2[k * 5 + 3];
    }
    if (row < N) {
        if (g == 0) {
            out[(size_t)row * 5 + 0] = o0 + bc2[0];
            out[(size_t)row * 5 + 4] = o1 + bc2[4];
        } else if (g == 1) {
            out[(size_t)row * 5 + 1] = o0 + bc2[1];
            out[(size_t)N * 5 + row] = 1.f / (1.f + expf(-(o1 + bp2[0])));
        } else if (g == 2) {
            out[(size_t)row * 5 + 2] = o0 + bc2[2];
        } else {
            out[(size_t)row * 5 + 3] = o0 + bc2[3];
        }
    }
}

extern "C" void kernel_launch(void* const* d_in, const int* in_sizes, int n_in,
                              void* d_out, int out_size, void* d_ws, size_t ws_size,
                              hipStream_t stream) {
    const float* node_feats = (const float*)d_in[0];
    const int*   edge_index = (const int*)d_in[1];
    const float* edge_feats = (const float*)d_in[2];
    const float* W_in = (const float*)d_in[3];
    const float* b_in = (const float*)d_in[4];
    const float* W_m1 = (const float*)d_in[5];
    const float* b_m1 = (const float*)d_in[6];
    const float* W_m2 = (const float*)d_in[7];
    const float* b_m2 = (const float*)d_in[8];
    const float* W_z  = (const float*)d_in[9];
    const float* b_z  = (const float*)d_in[10];
    const float* W_r  = (const float*)d_in[11];
    const float* b_r  = (const float*)d_in[12];
    const float* W_h  = (const float*)d_in[13];
    const float* b_h  = (const float*)d_in[14];
    const float* ln_s = (const float*)d_in[15];
    const float* ln_b = (const float*)d_in[16];
    const float* W_c1 = (const float*)d_in[17];
    const float* b_c1 = (const float*)d_in[18];
    const float* W_c2 = (const float*)d_in[19];
    const float* b_c2 = (const float*)d_in[20];
    const float* W_p1 = (const float*)d_in[21];
    const float* b_p1 = (const float*)d_in[22];
    const float* W_p2 = (const float*)d_in[23];
    const float* b_p2 = (const float*)d_in[24];

    const int N = in_sizes[0] / 8;
    const int E = in_sizes[2] / 4;

    char* ws = (char*)d_ws;
    size_t off = 0;
    auto alloc = [&](size_t bytes) { size_t p = off; off = (off + bytes + 255) & ~(size_t)255; return p; };
    const size_t o_hf = alloc((size_t)N * 128 * 4);   // f32 h
    const size_t o_X  = alloc((size_t)N * 256 * 4);   // f32 [agg|Xd->T]
    const size_t o_xs = alloc((size_t)N * 128 * 2);   // bf16 Xs gather table
    const size_t o_pk = alloc(((size_t)STEPS * 294912 + 32768) * 2);
    const size_t o_deg = alloc((size_t)N * 4);
    const size_t o_off = alloc((size_t)(N + 1) * 4);
    const size_t o_cur = alloc((size_t)N * 4);
    const size_t o_ex  = alloc((size_t)N * 4);
    const size_t o_bs  = alloc(1024 * 4);
    const size_t o_be  = alloc(1024 * 4);
    const size_t o_ss  = alloc((size_t)E * 4);
    const size_t o_ei  = alloc((size_t)E * 4);

    if (off > ws_size) {  // fail cleanly (diagnosable) instead of faulting
        hipMemsetAsync(d_out, 0, (size_t)out_size * 4, stream);
        return;
    }

    float* hf = (float*)(ws + o_hf);
    float* X  = (float*)(ws + o_X);
    unsigned short* Xs16 = (unsigned short*)(ws + o_xs);
    unsigned short* pH = (unsigned short*)(ws + o_pk) + (size_t)STEPS * 294912;

    // ---- CSR by dst ----
    hipMemsetAsync(ws + o_deg, 0, (size_t)N * 4, stream);
    hipMemsetAsync(ws + o_cur, 0, (size_t)N * 4, stream);
    hist_k<<<(E + 255) / 256, 256, 0, stream>>>(edge_index + E, (int*)(ws + o_deg), E);
    const int nb1 = (N + 1023) / 1024;
    scan1_k<<<nb1, 256, 0, stream>>>((int*)(ws + o_deg), (int*)(ws + o_ex), (int*)(ws + o_bs), N);
    scan2_k<<<1, 1024, 0, stream>>>((int*)(ws + o_bs), (int*)(ws + o_be), nb1);
    scan3_k<<<(N + 1 + 255) / 256, 256, 0, stream>>>((int*)(ws + o_ex), (int*)(ws + o_be),
                                                     (int*)(ws + o_off), N, E);
    scatter_k<<<(E + 255) / 256, 256, 0, stream>>>(edge_index, edge_index + E, (int*)(ws + o_off),
                                                   (int*)(ws + o_cur), (int*)(ws + o_ss),
                                                   (int*)(ws + o_ei), E);
    // ---- pack weights (hi+lo planes) ----
    pack_k<<<dim3(16, STEPS, 5), 256, 0, stream>>>(W_m1, W_m2, W_z, W_r, W_h,
                                                   (unsigned short*)(ws + o_pk));
    pack_head_k<<<8, 256, 0, stream>>>(W_c1, W_p1, pH);
    // ---- input projection (f32) ----
    proj_k<<<(N + 3) / 4, 256, 0, stream>>>(node_feats, W_in, b_in, hf, N);

    const int MB2 = (N + 63) / 64;

    for (int s = 0; s < STEPS; ++s) {
        const unsigned short* pk = (const unsigned short*)(ws + o_pk) + (size_t)s * 294912;
        const unsigned short* pkL = pk + 147456;
        // Xs (bf16) | Xd (f32) = h@[W1s|W1d]
        gemm_k<0><<<dim3(MB2, 2), 256, 0, stream>>>(hf, 128, pk, pkL, nullptr, nullptr,
                                                    X, 256, Xs16, N);
        // T[v] = sum relu(Xs16[src] + Xd + ef@Wef + b1) -> X[:,128:256]
        edge_k<<<(N + 3) / 4, 256, 0, stream>>>(X, Xs16, (int*)(ws + o_off), (int*)(ws + o_ss),
                                                (int*)(ws + o_ei), edge_feats,
                                                W_m1 + (size_t)s * 33280, b_m1 + (size_t)s * 128, N);
        // agg = T@W2 + deg*b_m2 -> X[:,0:128]
        gemm_k<1><<<dim3(MB2, 1), 256, 0, stream>>>(X + 128, 256, pk + 32768, pkL + 32768,
                                                    b_m2 + (size_t)s * 128, (int*)(ws + o_deg),
                                                    X, 256, nullptr, N);
        // fused gates + candidate + blend + LN (in-place hf; rh via LDS)
        zrh_k<<<MB2, 512, 0, stream>>>(hf, X,
                                       pk + 49152, pkL + 49152,     // Wz hi/lo
                                       pk + 81920, pkL + 81920,     // Wr hi/lo
                                       pk + 114688, pkL + 114688,   // Wh hi/lo
                                       b_z + (size_t)s * 128, b_r + (size_t)s * 128,
                                       b_h + (size_t)s * 128,
                                       ln_s + (size_t)s * 128, ln_b + (size_t)s * 128, N);
    }

    head_k<<<MB2, 256, 0, stream>>>(hf, pH, b_c1, b_p1, W_c2, b_c2, W_p2, b_p2,
                                    (float*)d_out, N);
}

// Round 17
// 2512.786 us; speedup vs baseline: 1.2455x; 1.2455x over previous
//
#include <hip/hip_runtime.h>

#define STEPS 6

typedef __attribute__((ext_vector_type(8))) short short8;
typedef __attribute__((ext_vector_type(4))) float f32x4;
typedef __attribute__((ext_vector_type(8))) float f32x8;

__device__ __forceinline__ float bf2f(unsigned int u16) {
    union { unsigned int u; float f; } v; v.u = u16 << 16; return v.f;
}
__device__ __forceinline__ unsigned int f2bf(float x) {
    union { float f; unsigned int u; } v; v.f = x;
    unsigned int r = v.u + 0x7fffu + ((v.u >> 16) & 1u);
    return r >> 16;
}
__device__ __forceinline__ void decompv(const f32x8& v, short8& hi, short8& lo) {
#pragma unroll
    for (int j = 0; j < 8; ++j) {
        float x = v[j];
        unsigned int h = f2bf(x);
        hi[j] = (short)h;
        lo[j] = (short)f2bf(x - bf2f(h));
    }
}
// async global->LDS, 16B per lane: LDS dst = uniform base + lane*16
__device__ __forceinline__ void gl_lds16(const void* g, void* s) {
    __builtin_amdgcn_global_load_lds(
        (const __attribute__((address_space(1))) unsigned int*)g,
        (__attribute__((address_space(3))) unsigned int*)s, 16, 0, 0);
}

// ---------------- CSR build ----------------
__global__ __launch_bounds__(256) void hist_k(const int* __restrict__ dst, int* __restrict__ deg, int E) {
    int e = blockIdx.x * 256 + threadIdx.x;
    if (e < E) atomicAdd(&deg[dst[e]], 1);
}

__global__ __launch_bounds__(256) void scan1_k(const int* __restrict__ in, int* __restrict__ ex,
                                               int* __restrict__ bs, int N) {
    __shared__ int sd[256];
    int t = threadIdx.x;
    int base = blockIdx.x * 1024 + t * 4;
    int v[4]; int s = 0;
#pragma unroll
    for (int i = 0; i < 4; ++i) { int idx = base + i; v[i] = idx < N ? in[idx] : 0; s += v[i]; }
    sd[t] = s; __syncthreads();
    for (int o = 1; o < 256; o <<= 1) {
        int x = (t >= o) ? sd[t - o] : 0;
        __syncthreads();
        sd[t] += x;
        __syncthreads();
    }
    int run = sd[t] - s;
#pragma unroll
    for (int i = 0; i < 4; ++i) { int idx = base + i; if (idx < N) ex[idx] = run; run += v[i]; }
    if (t == 255) bs[blockIdx.x] = sd[255];
}

__global__ __launch_bounds__(1024) void scan2_k(const int* __restrict__ bs, int* __restrict__ be, int nb) {
    __shared__ int sd[1024];
    int t = threadIdx.x;
    int v = (t < nb) ? bs[t] : 0;
    sd[t] = v; __syncthreads();
    for (int o = 1; o < 1024; o <<= 1) {
        int x = (t >= o) ? sd[t - o] : 0;
        __syncthreads();
        sd[t] += x;
        __syncthreads();
    }
    if (t < nb) be[t] = sd[t] - v;
}

__global__ __launch_bounds__(256) void scan3_k(const int* __restrict__ ex, const int* __restrict__ be,
                                               int* __restrict__ offs, int N, int E) {
    int i = blockIdx.x * 256 + threadIdx.x;
    if (i < N) offs[i] = ex[i] + be[i >> 10];
    if (i == N) offs[N] = E;
}

__global__ __launch_bounds__(256) void scatter_k(const int* __restrict__ src, const int* __restrict__ dst,
                                                 const float4* __restrict__ ef,
                                                 const int* __restrict__ offs,
                                                 int* __restrict__ cursor, int* __restrict__ src_sorted,
                                                 uint2* __restrict__ ef16_sorted, int E) {
    int e = blockIdx.x * 256 + threadIdx.x;
    if (e >= E) return;
    int d = dst[e];
    int pos = offs[d] + atomicAdd(&cursor[d], 1);
    src_sorted[pos] = src[e];
    float4 f = ef[e];
    uint2 p;
    p.x = f2bf(f.x) | (f2bf(f.y) << 16);
    p.y = f2bf(f.z) | (f2bf(f.w) << 16);
    ef16_sorted[pos] = p;
}

// ---------------- weight packing: hi+lo bf16 planes, B-fragment order ----------------
// frag addr: ((ct*KS + ks)*64 + lane)*8 + j ; k = ks*32 + (lane>>4)*8 + j, col = ct*16 + (lane&15)
// per-step (stride 294912 elems): hi plane at +0, lo plane at +147456
// mat offsets (elems): W1:0 (32768), W2:32768 (16384), Wz:49152, Wr:81920, Wh:114688
__global__ __launch_bounds__(256) void pack_k(const float* __restrict__ W_m1, const float* __restrict__ W_m2,
                                              const float* __restrict__ W_z, const float* __restrict__ W_r,
                                              const float* __restrict__ W_h, unsigned short* __restrict__ packed) {
    const int s = blockIdx.y, mat = blockIdx.z;
    const int t = blockIdx.x * 256 + threadIdx.x;
    const int lane = t & 63;
    int KS, width; size_t moff;
    if (mat == 0)      { KS = 4; width = 256; moff = 0; }
    else if (mat == 1) { KS = 4; width = 128; moff = 32768; }
    else if (mat == 2) { KS = 8; width = 128; moff = 49152; }
    else if (mat == 3) { KS = 8; width = 128; moff = 81920; }
    else               { KS = 8; width = 128; moff = 114688; }
    const int total = (width >> 4) * KS * 64;
    if (t >= total) return;
    const int ks = (t >> 6) % KS;
    const int ct = (t >> 6) / KS;
    const int col = ct * 16 + (lane & 15);
    const int kb = ks * 32 + (lane >> 4) * 8;
    unsigned short* dh = packed + (size_t)s * 294912 + moff;
    unsigned short* dl = dh + 147456;
#pragma unroll
    for (int j = 0; j < 8; ++j) {
        const int k = kb + j;
        float v;
        if (mat == 0) {
            const float* W = W_m1 + (size_t)s * 260 * 128;
            v = (col < 128) ? W[k * 128 + col] : W[(128 + k) * 128 + (col - 128)];
        } else if (mat == 1) {
            v = W_m2[(size_t)s * 16384 + k * 128 + col];
        } else if (mat == 2) {
            v = W_z[(size_t)s * 32768 + k * 128 + col];
        } else if (mat == 3) {
            v = W_r[(size_t)s * 32768 + k * 128 + col];
        } else {
            v = W_h[(size_t)s * 32768 + k * 128 + col];
        }
        unsigned int hb = f2bf(v);
        dh[(size_t)t * 8 + j] = (unsigned short)hb;
        dl[(size_t)t * 8 + j] = (unsigned short)f2bf(v - bf2f(hb));
    }
}

// ---------------- head weight packing: [Wc1|Wp1] as 128x128, hi+lo (16384 elems each) ----------------
__global__ __launch_bounds__(256) void pack_head_k(const float* __restrict__ Wc1,
                                                   const float* __restrict__ Wp1,
                                                   unsigned short* __restrict__ dst) {
    const int t = blockIdx.x * 256 + threadIdx.x;   // 0..2047
    if (t >= 2048) return;
    const int lane = t & 63;
    const int ks = (t >> 6) & 3;
    const int ct = (t >> 6) >> 2;
    const int col = ct * 16 + (lane & 15);
    const int kb = ks * 32 + (lane >> 4) * 8;
    unsigned short* dh = dst;
    unsigned short* dl = dst + 16384;
#pragma unroll
    for (int j = 0; j < 8; ++j) {
        const int k = kb + j;
        float v = (col < 64) ? Wc1[k * 64 + col] : Wp1[k * 64 + (col - 64)];
        unsigned int hb = f2bf(v);
        dh[(size_t)t * 8 + j] = (unsigned short)hb;
        dl[(size_t)t * 8 + j] = (unsigned short)f2bf(v - bf2f(hb));
    }
}

// ---------------- input projection -> f32 h ----------------
__global__ __launch_bounds__(256) void proj_k(const float* __restrict__ nf, const float* __restrict__ Win,
                                              const float* __restrict__ bin,
                                              float* __restrict__ hf, int N) {
    const int lane = threadIdx.x & 63, wave = threadIdx.x >> 6;
    const int i = blockIdx.x * 4 + wave;
    if (i >= N) return;
    const int c0 = lane * 2;
    float a0 = bin[c0], a1 = bin[c0 + 1];
#pragma unroll
    for (int q = 0; q < 8; ++q) {
        float x = nf[(size_t)i * 8 + q];
        a0 += x * Win[q * 128 + c0];
        a1 += x * Win[q * 128 + c0 + 1];
    }
    hf[(size_t)i * 128 + c0] = a0;
    hf[(size_t)i * 128 + c0 + 1] = a1;
}

// ---------------- f32-accurate MFMA GEMM, direct L2 weight reads, no barriers ----------------
// MODE 0: [Xs|Xd] = h@[W1s|W1d] : A=hf lda=128; cgrp0 -> Xs bf16 [N,128]; cgrp1 -> Xd f32 X[:,128:256]
// MODE 1: agg = T@W2 + deg*b : A=X+128 lda=256, out f32 X[:,0:128]
template <int MODE>
__global__ __launch_bounds__(256, 4) void gemm_k(const float* __restrict__ A, int lda,
                                                 const unsigned short* __restrict__ pkh,
                                                 const unsigned short* __restrict__ pkl,
                                                 const float* __restrict__ bias,
                                                 const int* __restrict__ deg,
                                                 float* __restrict__ out, int ldo,
                                                 unsigned short* __restrict__ out_b,
                                                 int Nrows) {
    const int lane = threadIdx.x & 63;
    const int wave = threadIdx.x >> 6;
    const int l15 = lane & 15, l16 = lane >> 4;
    const int mrow = blockIdx.x * 64 + wave * 16;
    const int cgrp = blockIdx.y;

    int r0 = mrow + l15; if (r0 >= Nrows) r0 = 0;
    const float* ap = A + (size_t)r0 * lda;

    f32x4 acc[8];
#pragma unroll
    for (int ct = 0; ct < 8; ++ct) acc[ct] = (f32x4){0.f, 0.f, 0.f, 0.f};

    for (int ks = 0; ks < 4; ++ks) {
        const f32x8 av = *(const f32x8*)(ap + ks * 32 + l16 * 8);
        short8 ahi, alo;
        decompv(av, ahi, alo);
#pragma unroll
        for (int ct = 0; ct < 8; ++ct) {
            const size_t fb = (((size_t)(cgrp * 8 + ct) * 4 + ks) << 10) + lane * 16;
            const short8 wh = *(const short8*)((const char*)pkh + fb);
            const short8 wl = *(const short8*)((const char*)pkl + fb);
            acc[ct] = __builtin_amdgcn_mfma_f32_16x16x32_bf16(ahi, wh, acc[ct], 0, 0, 0);
            acc[ct] = __builtin_amdgcn_mfma_f32_16x16x32_bf16(alo, wh, acc[ct], 0, 0, 0);
            acc[ct] = __builtin_amdgcn_mfma_f32_16x16x32_bf16(ahi, wl, acc[ct], 0, 0, 0);
        }
    }
#pragma unroll
    for (int ct = 0; ct < 8; ++ct) {
        const int col = cgrp * 128 + ct * 16 + l15;
#pragma unroll
        for (int r = 0; r < 4; ++r) {
            const int row = mrow + l16 * 4 + r;
            if (row >= Nrows) continue;
            float v = acc[ct][r];
            if (MODE == 0) {
                if (cgrp == 0) out_b[(size_t)row * 128 + col] = (unsigned short)f2bf(v);
                else           out[(size_t)row * ldo + col] = v;   // col in 128..255 -> Xd slot
            } else {
                v += bias[col] * (float)deg[row];
                out[(size_t)row * ldo + col] = v;
            }
        }
    }
}

// ---------------- fused z,r,rh,hn,blend,LN — 512 thr: 4 rowgrp x 2 colgrp, 16 rows x 64 cols/wave ----------------
__global__ __launch_bounds__(512, 4) void zrh_k(float* __restrict__ hf,
                                                const float* __restrict__ X,  // [N,256]: 0:128 agg
                                                const unsigned short* __restrict__ pzh, const unsigned short* __restrict__ pzl,
                                                const unsigned short* __restrict__ prh, const unsigned short* __restrict__ prl,
                                                const unsigned short* __restrict__ phh, const unsigned short* __restrict__ phl,
                                                const float* __restrict__ bz, const float* __restrict__ br,
                                                const float* __restrict__ bh,
                                                const float* __restrict__ lns, const float* __restrict__ lnb,
                                                int N) {
    __shared__ char stg[49152];   // phase1: 48 weight lines x 1KB; phase2+: rhs[4][2112] f32 + LN partials
    float* rhs = reinterpret_cast<float*>(stg);
    float* lnp = reinterpret_cast<float*>(stg + 33792);  // [4][2][16][2]
    const int lane = threadIdx.x & 63;
    const int wave = threadIdx.x >> 6;           // 0..7
    const int rowgrp = wave >> 1, colgrp = wave & 1;
    const int l15 = lane & 15, l16 = lane >> 4;
    const int mrow = blockIdx.x * 64 + rowgrp * 16;

    int r0 = mrow + l15; if (r0 >= N) r0 = 0;

    f32x4 zac[4], rac[4], hac[4];
#pragma unroll
    for (int c = 0; c < 4; ++c) {
        zac[c] = (f32x4){0.f, 0.f, 0.f, 0.f};
        rac[c] = (f32x4){0.f, 0.f, 0.f, 0.f};
        hac[c] = (f32x4){0.f, 0.f, 0.f, 0.f};
    }

    const unsigned short* wsrc[6] = {pzh, pzl, prh, prl, phh, phl};

    // ---- phase 1: staged weights, counted vmcnt, 2 barriers/ks ----
    f32x8 acur = *(const f32x8*)(hf + (size_t)r0 * 128 + l16 * 8);
    for (int ks = 0; ks < 8; ++ks) {
        const int nplanes = (ks >= 4) ? 6 : 4;
        for (int i = 0; i < nplanes; ++i)
            gl_lds16((const char*)wsrc[i] + (((size_t)(wave * 8 + ks)) << 10) + lane * 16,
                     &stg[(i * 8 + wave) << 10]);
        f32x8 anext;
        if (ks < 7) {
            const int kn = (ks + 1) * 32 + l16 * 8;
            const float* ap = (kn < 128) ? (hf + (size_t)r0 * 128 + kn)
                                         : (X + (size_t)r0 * 256 + (kn - 128));
            f32x4 pa = *(const f32x4*)ap;
            f32x4 pb = *(const f32x4*)(ap + 4);
            anext[0] = pa[0]; anext[1] = pa[1]; anext[2] = pa[2]; anext[3] = pa[3];
            anext[4] = pb[0]; anext[5] = pb[1]; anext[6] = pb[2]; anext[7] = pb[3];
        }
        short8 ahi, alo;
        decompv(acur, ahi, alo);
        if (ks < 7) asm volatile("s_waitcnt vmcnt(2)" ::: "memory");
        else        asm volatile("s_waitcnt vmcnt(0)" ::: "memory");
        __builtin_amdgcn_sched_barrier(0);
        __builtin_amdgcn_s_barrier();
        __builtin_amdgcn_sched_barrier(0);
#pragma unroll
        for (int c = 0; c < 4; ++c) {
            const int ct = colgrp * 4 + c;
            const short8 wzh = *(const short8*)(stg + ((0 * 8 + ct) << 10) + lane * 16);
            const short8 wzl = *(const short8*)(stg + ((1 * 8 + ct) << 10) + lane * 16);
            const short8 wrh = *(const short8*)(stg + ((2 * 8 + ct) << 10) + lane * 16);
            const short8 wrl = *(const short8*)(stg + ((3 * 8 + ct) << 10) + lane * 16);
            zac[c] = __builtin_amdgcn_mfma_f32_16x16x32_bf16(ahi, wzh, zac[c], 0, 0, 0);
            zac[c] = __builtin_amdgcn_mfma_f32_16x16x32_bf16(alo, wzh, zac[c], 0, 0, 0);
            zac[c] = __builtin_amdgcn_mfma_f32_16x16x32_bf16(ahi, wzl, zac[c], 0, 0, 0);
            rac[c] = __builtin_amdgcn_mfma_f32_16x16x32_bf16(ahi, wrh, rac[c], 0, 0, 0);
            rac[c] = __builtin_amdgcn_mfma_f32_16x16x32_bf16(alo, wrh, rac[c], 0, 0, 0);
            rac[c] = __builtin_amdgcn_mfma_f32_16x16x32_bf16(ahi, wrl, rac[c], 0, 0, 0);
            if (ks >= 4) {
                const short8 wbh = *(const short8*)(stg + ((4 * 8 + ct) << 10) + lane * 16);
                const short8 wbl = *(const short8*)(stg + ((5 * 8 + ct) << 10) + lane * 16);
                hac[c] = __builtin_amdgcn_mfma_f32_16x16x32_bf16(ahi, wbh, hac[c], 0, 0, 0);
                hac[c] = __builtin_amdgcn_mfma_f32_16x16x32_bf16(alo, wbh, hac[c], 0, 0, 0);
                hac[c] = __builtin_amdgcn_mfma_f32_16x16x32_bf16(ahi, wbl, hac[c], 0, 0, 0);
            }
        }
        __builtin_amdgcn_sched_barrier(0);
        __builtin_amdgcn_s_barrier();
        acur = anext;
    }

    // ---- phase 2: z = sigmoid (keep); rh = sigmoid(r)*h -> LDS rhs[rowgrp][rowl][col] ----
#pragma unroll
    for (int c = 0; c < 4; ++c) {
        const int col = (colgrp * 4 + c) * 16 + l15;
#pragma unroll
        for (int r = 0; r < 4; ++r) {
            const int rowl = l16 * 4 + r;
            const int row = mrow + rowl;
            const size_t idx = (size_t)(row < N ? row : 0) * 128 + col;
            float zp = zac[c][r] + bz[col];
            zac[c][r] = 1.f / (1.f + expf(-zp));
            float rp = rac[c][r] + br[col];
            float rr = 1.f / (1.f + expf(-rp));
            rhs[rowgrp * 2112 + rowl * 132 + col] = rr * hf[idx];
        }
    }
    __syncthreads();

    // ---- phase 3: hn += rh @ Wh_top (K=128), weights direct from L2 ----
    for (int ks = 0; ks < 4; ++ks) {
        const f32x8 v = *(const f32x8*)(rhs + rowgrp * 2112 + l15 * 132 + (ks * 4 + l16) * 8);
        short8 ahi, alo;
        decompv(v, ahi, alo);
#pragma unroll
        for (int c = 0; c < 4; ++c) {
            const int ct = colgrp * 4 + c;
            const size_t fb = (((size_t)(ct * 8 + ks)) << 10) + lane * 16;
            const short8 wh = *(const short8*)((const char*)phh + fb);
            const short8 wl = *(const short8*)((const char*)phl + fb);
            hac[c] = __builtin_amdgcn_mfma_f32_16x16x32_bf16(ahi, wh, hac[c], 0, 0, 0);
            hac[c] = __builtin_amdgcn_mfma_f32_16x16x32_bf16(alo, wh, hac[c], 0, 0, 0);
            hac[c] = __builtin_amdgcn_mfma_f32_16x16x32_bf16(ahi, wl, hac[c], 0, 0, 0);
        }
    }

    // ---- phase 4: blend + cross-wave LayerNorm -> hf ----
#pragma unroll
    for (int c = 0; c < 4; ++c) {
        const int col = (colgrp * 4 + c) * 16 + l15;
#pragma unroll
        for (int r = 0; r < 4; ++r) {
            const int row = mrow + l16 * 4 + r;
            const size_t idx = (size_t)(row < N ? row : 0) * 128 + col;
            float hn = tanhf(hac[c][r] + bh[col]);
            float zz = zac[c][r];
            hac[c][r] = (1.f - zz) * hf[idx] + zz * hn;
        }
    }
    float sr[4], ssr[4];
#pragma unroll
    for (int r = 0; r < 4; ++r) {
        float s = 0.f, ss = 0.f;
#pragma unroll
        for (int c = 0; c < 4; ++c) {
            float y = hac[c][r];
            s += y; ss += y * y;
        }
#pragma unroll
        for (int m = 1; m < 16; m <<= 1) {
            s += __shfl_xor(s, m, 64);
            ss += __shfl_xor(ss, m, 64);
        }
        sr[r] = s; ssr[r] = ss;
        if (l15 == 0) {
            float* p = lnp + (((rowgrp * 2 + colgrp) * 16) + (l16 * 4 + r)) * 2;
            p[0] = s; p[1] = ss;
        }
    }
    __syncthreads();
#pragma unroll
    for (int r = 0; r < 4; ++r) {
        const int rowl = l16 * 4 + r;
        const int row = mrow + rowl;
        const float* po = lnp + (((rowgrp * 2 + (colgrp ^ 1)) * 16) + rowl) * 2;
        float s = sr[r] + po[0];
        float ss = ssr[r] + po[1];
        float mean = s * (1.f / 128.f);
        float var = ss * (1.f / 128.f) - mean * mean;
        float inv = rsqrtf(var + 1e-6f);
        if (row < N) {
#pragma unroll
            for (int c = 0; c < 4; ++c) {
                const int col = (colgrp * 4 + c) * 16 + l15;
                hf[(size_t)row * 128 + col] = (hac[c][r] - mean) * inv * lns[col] + lnb[col];
            }
        }
    }
}

// ---------------- edge accumulate: T[v] = sum relu(Xs16[src]+Xd[v]+ef16@Wef+b1) -> X[:,128:256] (f32) ----
__global__ __launch_bounds__(256) void edge_k(float* __restrict__ X,
                                              const unsigned short* __restrict__ Xs16,
                                              const int* __restrict__ offs,
                                              const int* __restrict__ src_sorted,
                                              const uint2* __restrict__ ef16_sorted,
                                              const float* __restrict__ Wm1_s,
                                              const float* __restrict__ bm1_s,
                                              int N) {
    const int lane = threadIdx.x & 63, wave = threadIdx.x >> 6;
    const int v = blockIdx.x * 4 + wave;
    if (v >= N) return;
    const int c0 = lane * 2;
    const float base0 = X[(size_t)v * 256 + 128 + c0] + bm1_s[c0];
    const float base1 = X[(size_t)v * 256 + 129 + c0] + bm1_s[c0 + 1];
    const float w0x = Wm1_s[256 * 128 + c0], w0y = Wm1_s[256 * 128 + c0 + 1];
    const float w1x = Wm1_s[257 * 128 + c0], w1y = Wm1_s[257 * 128 + c0 + 1];
    const float w2x = Wm1_s[258 * 128 + c0], w2y = Wm1_s[258 * 128 + c0 + 1];
    const float w3x = Wm1_s[259 * 128 + c0], w3y = Wm1_s[259 * 128 + c0 + 1];
    float acc0 = 0.f, acc1 = 0.f;
    const int beg = offs[v], end = offs[v + 1];
    for (int i = beg; i < end; ++i) {
        int sn = src_sorted[i];
        uint2 efp = ef16_sorted[i];
        float efa = bf2f(efp.x & 0xffffu), efb = bf2f(efp.x >> 16);
        float efc = bf2f(efp.y & 0xffffu), efd = bf2f(efp.y >> 16);
        unsigned int xs = *reinterpret_cast<const unsigned int*>(Xs16 + (size_t)sn * 128 + c0);
        float e0 = efa * w0x + efb * w1x + efc * w2x + efd * w3x;
        float e1 = efa * w0y + efb * w1y + efc * w2y + efd * w3y;
        acc0 += fmaxf(bf2f(xs & 0xffffu) + base0 + e0, 0.f);
        acc1 += fmaxf(bf2f(xs >> 16) + base1 + e1, 0.f);
    }
    X[(size_t)v * 256 + 128 + c0] = acc0;   // T overwrites Xd (consumed above)
    X[(size_t)v * 256 + 129 + c0] = acc1;
}

// ---------------- heads: MFMA stage-1 (h@[Wc1|Wp1]) + LDS stage-2 ----------------
__global__ __launch_bounds__(256, 4) void head_k(const float* __restrict__ hf,
                                                 const unsigned short* __restrict__ pH,  // hi; lo at +16384
                                                 const float* __restrict__ bc1, const float* __restrict__ bp1,
                                                 const float* __restrict__ Wc2, const float* __restrict__ bc2,
                                                 const float* __restrict__ Wp2, const float* __restrict__ bp2,
                                                 float* __restrict__ out, int N) {
    __shared__ float tls[4][16][132];
    const int lane = threadIdx.x & 63, wave = threadIdx.x >> 6;
    const int l15 = lane & 15, l16 = lane >> 4;
    const int mrow = blockIdx.x * 64 + wave * 16;
    const unsigned short* pHl = pH + 16384;

    int r0 = mrow + l15; if (r0 >= N) r0 = 0;
    const float* ap = hf + (size_t)r0 * 128;

    f32x4 acc[8];
#pragma unroll
    for (int ct = 0; ct < 8; ++ct) acc[ct] = (f32x4){0.f, 0.f, 0.f, 0.f};

    for (int ks = 0; ks < 4; ++ks) {
        const f32x8 av = *(const f32x8*)(ap + ks * 32 + l16 * 8);
        short8 ahi, alo;
        decompv(av, ahi, alo);
#pragma unroll
        for (int ct = 0; ct < 8; ++ct) {
            const size_t fb = (((size_t)(ct * 4 + ks)) << 10) + lane * 16;
            const short8 wh = *(const short8*)((const char*)pH + fb);
            const short8 wl = *(const short8*)((const char*)pHl + fb);
            acc[ct] = __builtin_amdgcn_mfma_f32_16x16x32_bf16(ahi, wh, acc[ct], 0, 0, 0);
            acc[ct] = __builtin_amdgcn_mfma_f32_16x16x32_bf16(alo, wh, acc[ct], 0, 0, 0);
            acc[ct] = __builtin_amdgcn_mfma_f32_16x16x32_bf16(ahi, wl, acc[ct], 0, 0, 0);
        }
    }
    // relu + bias -> per-wave LDS tile (cols 0:64 = cls-hidden, 64:128 = prob-hidden)
#pragma unroll
    for (int ct = 0; ct < 8; ++ct) {
        const int col = ct * 16 + l15;
        const float b = (col < 64) ? bc1[col] : bp1[col - 64];
#pragma unroll
        for (int r = 0; r < 4; ++r) {
            const int rowl = l16 * 4 + r;
            tls[wave][rowl][col] = fmaxf(acc[ct][r] + b, 0.f);
        }
    }
    // stage 2: 4-lane groups per row
    const int rowl = lane & 15;
    const int g = lane >> 4;
    const int row = mrow + rowl;
    const float* tr = &tls[wave][rowl][0];
    float o0 = 0.f, o1 = 0.f;
    if (g == 0) {
        for (int k = 0; k < 64; ++k) { float tv = tr[k]; o0 += tv * Wc2[k * 5 + 0]; o1 += tv * Wc2[k * 5 + 4]; }
    } else if (g == 1) {
        for (int k = 0; k < 64; ++k) { o0 += tr[k] * Wc2[k * 5 + 1]; o1 += tr[64 + k] * Wp2[k]; }
    } else if (g == 2) {
        for (int k = 0; k < 64; ++k) o0 += tr[k] * Wc2[k * 5 + 2];
    } else {
        for (int k = 0; k < 64; ++k) o0 += tr[k] * Wc2[k * 5 + 3];
    }
    if (row < N) {
        if (g == 0) {
            out[(size_t)row * 5 + 0] = o0 + bc2[0];
            out[(size_t)row * 5 + 4] = o1 + bc2[4];
        } else if (g == 1) {
            out[(size_t)row * 5 + 1] = o0 + bc2[1];
            out[(size_t)N * 5 + row] = 1.f / (1.f + expf(-(o1 + bp2[0])));
        } else if (g == 2) {
            out[(size_t)row * 5 + 2] = o0 + bc2[2];
        } else {
            out[(size_t)row * 5 + 3] = o0 + bc2[3];
        }
    }
}

extern "C" void kernel_launch(void* const* d_in, const int* in_sizes, int n_in,
                              void* d_out, int out_size, void* d_ws, size_t ws_size,
                              hipStream_t stream) {
    const float* node_feats = (const float*)d_in[0];
    const int*   edge_index = (const int*)d_in[1];
    const float* edge_feats = (const float*)d_in[2];
    const float* W_in = (const float*)d_in[3];
    const float* b_in = (const float*)d_in[4];
    const float* W_m1 = (const float*)d_in[5];
    const float* b_m1 = (const float*)d_in[6];
    const float* W_m2 = (const float*)d_in[7];
    const float* b_m2 = (const float*)d_in[8];
    const float* W_z  = (const float*)d_in[9];
    const float* b_z  = (const float*)d_in[10];
    const float* W_r  = (const float*)d_in[11];
    const float* b_r  = (const float*)d_in[12];
    const float* W_h  = (const float*)d_in[13];
    const float* b_h  = (const float*)d_in[14];
    const float* ln_s = (const float*)d_in[15];
    const float* ln_b = (const float*)d_in[16];
    const float* W_c1 = (const float*)d_in[17];
    const float* b_c1 = (const float*)d_in[18];
    const float* W_c2 = (const float*)d_in[19];
    const float* b_c2 = (const float*)d_in[20];
    const float* W_p1 = (const float*)d_in[21];
    const float* b_p1 = (const float*)d_in[22];
    const float* W_p2 = (const float*)d_in[23];
    const float* b_p2 = (const float*)d_in[24];

    const int N = in_sizes[0] / 8;
    const int E = in_sizes[2] / 4;

    char* ws = (char*)d_ws;
    size_t off = 0;
    auto alloc = [&](size_t bytes) { size_t p = off; off = (off + bytes + 255) & ~(size_t)255; return p; };
    const size_t o_hf = alloc((size_t)N * 128 * 4);   // f32 h
    const size_t o_X  = alloc((size_t)N * 256 * 4);   // f32 [agg|Xd->T]
    const size_t o_xs = alloc((size_t)N * 128 * 2);   // bf16 Xs gather table
    const size_t o_pk = alloc(((size_t)STEPS * 294912 + 32768) * 2);
    const size_t o_deg = alloc((size_t)N * 4);
    const size_t o_off = alloc((size_t)(N + 1) * 4);
    const size_t o_cur = alloc((size_t)N * 4);
    const size_t o_ex  = alloc((size_t)N * 4);
    const size_t o_bs  = alloc(1024 * 4);
    const size_t o_be  = alloc(1024 * 4);
    const size_t o_ss  = alloc((size_t)E * 4);   // src_sorted
    const size_t o_ef  = alloc((size_t)E * 8);   // ef16_sorted (4x bf16)

    if (off > ws_size) {  // fail cleanly (diagnosable) instead of faulting
        hipMemsetAsync(d_out, 0, (size_t)out_size * 4, stream);
        return;
    }

    float* hf = (float*)(ws + o_hf);
    float* X  = (float*)(ws + o_X);
    unsigned short* Xs16 = (unsigned short*)(ws + o_xs);
    unsigned short* pH = (unsigned short*)(ws + o_pk) + (size_t)STEPS * 294912;

    // ---- CSR by dst ----
    hipMemsetAsync(ws + o_deg, 0, (size_t)N * 4, stream);
    hipMemsetAsync(ws + o_cur, 0, (size_t)N * 4, stream);
    hist_k<<<(E + 255) / 256, 256, 0, stream>>>(edge_index + E, (int*)(ws + o_deg), E);
    const int nb1 = (N + 1023) / 1024;
    scan1_k<<<nb1, 256, 0, stream>>>((int*)(ws + o_deg), (int*)(ws + o_ex), (int*)(ws + o_bs), N);
    scan2_k<<<1, 1024, 0, stream>>>((int*)(ws + o_bs), (int*)(ws + o_be), nb1);
    scan3_k<<<(N + 1 + 255) / 256, 256, 0, stream>>>((int*)(ws + o_ex), (int*)(ws + o_be),
                                                     (int*)(ws + o_off), N, E);
    scatter_k<<<(E + 255) / 256, 256, 0, stream>>>(edge_index, edge_index + E,
                                                   (const float4*)edge_feats, (int*)(ws + o_off),
                                                   (int*)(ws + o_cur), (int*)(ws + o_ss),
                                                   (uint2*)(ws + o_ef), E);
    // ---- pack weights (hi+lo planes) ----
    pack_k<<<dim3(16, STEPS, 5), 256, 0, stream>>>(W_m1, W_m2, W_z, W_r, W_h,
                                                   (unsigned short*)(ws + o_pk));
    pack_head_k<<<8, 256, 0, stream>>>(W_c1, W_p1, pH);
    // ---- input projection (f32) ----
    proj_k<<<(N + 3) / 4, 256, 0, stream>>>(node_feats, W_in, b_in, hf, N);

    const int MB2 = (N + 63) / 64;

    for (int s = 0; s < STEPS; ++s) {
        const unsigned short* pk = (const unsigned short*)(ws + o_pk) + (size_t)s * 294912;
        const unsigned short* pkL = pk + 147456;
        // Xs (bf16) | Xd (f32) = h@[W1s|W1d]
        gemm_k<0><<<dim3(MB2, 2), 256, 0, stream>>>(hf, 128, pk, pkL, nullptr, nullptr,
                                                    X, 256, Xs16, N);
        // T[v] = sum relu(Xs16[src] + Xd + ef16@Wef + b1) -> X[:,128:256]
        edge_k<<<(N + 3) / 4, 256, 0, stream>>>(X, Xs16, (int*)(ws + o_off), (int*)(ws + o_ss),
                                                (const uint2*)(ws + o_ef),
                                                W_m1 + (size_t)s * 33280, b_m1 + (size_t)s * 128, N);
        // agg = T@W2 + deg*b_m2 -> X[:,0:128]
        gemm_k<1><<<dim3(MB2, 1), 256, 0, stream>>>(X + 128, 256, pk + 32768, pkL + 32768,
                                                    b_m2 + (size_t)s * 128, (int*)(ws + o_deg),
                                                    X, 256, nullptr, N);
        // fused gates + candidate + blend + LN (in-place hf; rh via LDS)
        zrh_k<<<MB2, 512, 0, stream>>>(hf, X,
                                       pk + 49152, pkL + 49152,     // Wz hi/lo
                                       pk + 81920, pkL + 81920,     // Wr hi/lo
                                       pk + 114688, pkL + 114688,   // Wh hi/lo
                                       b_z + (size_t)s * 128, b_r + (size_t)s * 128,
                                       b_h + (size_t)s * 128,
                                       ln_s + (size_t)s * 128, ln_b + (size_t)s * 128, N);
    }

    head_k<<<MB2, 256, 0, stream>>>(hf, pH, b_c1, b_p1, W_c2, b_c2, W_p2, b_p2,
                                    (float*)d_out, N);
}

// Round 18
// 2036.062 us; speedup vs baseline: 1.5372x; 1.2341x over previous
//
#include <hip/hip_runtime.h>

#define STEPS 6

typedef __attribute__((ext_vector_type(8))) short short8;
typedef __attribute__((ext_vector_type(4))) float f32x4;
typedef __attribute__((ext_vector_type(8))) float f32x8;

__device__ __forceinline__ float bf2f(unsigned int u16) {
    union { unsigned int u; float f; } v; v.u = u16 << 16; return v.f;
}
__device__ __forceinline__ unsigned int f2bf(float x) {
    union { float f; unsigned int u; } v; v.f = x;
    unsigned int r = v.u + 0x7fffu + ((v.u >> 16) & 1u);
    return r >> 16;
}
__device__ __forceinline__ void decompv(const f32x8& v, short8& hi, short8& lo) {
#pragma unroll
    for (int j = 0; j < 8; ++j) {
        float x = v[j];
        unsigned int h = f2bf(x);
        hi[j] = (short)h;
        lo[j] = (short)f2bf(x - bf2f(h));
    }
}
// async global->LDS, 16B per lane: LDS dst = uniform base + lane*16
__device__ __forceinline__ void gl_lds16(const void* g, void* s) {
    __builtin_amdgcn_global_load_lds(
        (const __attribute__((address_space(1))) unsigned int*)g,
        (__attribute__((address_space(3))) unsigned int*)s, 16, 0, 0);
}

// ---------------- CSR build ----------------
__global__ __launch_bounds__(256) void hist_k(const int* __restrict__ dst, int* __restrict__ deg, int E) {
    int e = blockIdx.x * 256 + threadIdx.x;
    if (e < E) atomicAdd(&deg[dst[e]], 1);
}

__global__ __launch_bounds__(256) void scan1_k(const int* __restrict__ in, int* __restrict__ ex,
                                               int* __restrict__ bs, int N) {
    __shared__ int sd[256];
    int t = threadIdx.x;
    int base = blockIdx.x * 1024 + t * 4;
    int v[4]; int s = 0;
#pragma unroll
    for (int i = 0; i < 4; ++i) { int idx = base + i; v[i] = idx < N ? in[idx] : 0; s += v[i]; }
    sd[t] = s; __syncthreads();
    for (int o = 1; o < 256; o <<= 1) {
        int x = (t >= o) ? sd[t - o] : 0;
        __syncthreads();
        sd[t] += x;
        __syncthreads();
    }
    int run = sd[t] - s;
#pragma unroll
    for (int i = 0; i < 4; ++i) { int idx = base + i; if (idx < N) ex[idx] = run; run += v[i]; }
    if (t == 255) bs[blockIdx.x] = sd[255];
}

__global__ __launch_bounds__(1024) void scan2_k(const int* __restrict__ bs, int* __restrict__ be, int nb) {
    __shared__ int sd[1024];
    int t = threadIdx.x;
    int v = (t < nb) ? bs[t] : 0;
    sd[t] = v; __syncthreads();
    for (int o = 1; o < 1024; o <<= 1) {
        int x = (t >= o) ? sd[t - o] : 0;
        __syncthreads();
        sd[t] += x;
        __syncthreads();
    }
    if (t < nb) be[t] = sd[t] - v;
}

__global__ __launch_bounds__(256) void scan3_k(const int* __restrict__ ex, const int* __restrict__ be,
                                               int* __restrict__ offs, int N, int E) {
    int i = blockIdx.x * 256 + threadIdx.x;
    if (i < N) offs[i] = ex[i] + be[i >> 10];
    if (i == N) offs[N] = E;
}

__global__ __launch_bounds__(256) void scatter_k(const int* __restrict__ src, const int* __restrict__ dst,
                                                 const float4* __restrict__ ef,
                                                 const int* __restrict__ offs,
                                                 int* __restrict__ cursor, int* __restrict__ src_sorted,
                                                 uint2* __restrict__ ef16_sorted, int E) {
    int e = blockIdx.x * 256 + threadIdx.x;
    if (e >= E) return;
    int d = dst[e];
    int pos = offs[d] + atomicAdd(&cursor[d], 1);
    src_sorted[pos] = src[e];
    float4 f = ef[e];
    uint2 p;
    p.x = f2bf(f.x) | (f2bf(f.y) << 16);
    p.y = f2bf(f.z) | (f2bf(f.w) << 16);
    ef16_sorted[pos] = p;
}

// ---------------- weight packing: hi+lo bf16 planes, B-fragment order ----------------
// frag addr: ((ct*KS + ks)*64 + lane)*8 + j ; k = ks*32 + (lane>>4)*8 + j, col = ct*16 + (lane&15)
// per-step (stride 294912 elems): hi plane at +0, lo plane at +147456
// mat offsets (elems): W1:0 (32768), W2:32768 (16384), Wz:49152, Wr:81920, Wh:114688
__global__ __launch_bounds__(256) void pack_k(const float* __restrict__ W_m1, const float* __restrict__ W_m2,
                                              const float* __restrict__ W_z, const float* __restrict__ W_r,
                                              const float* __restrict__ W_h, unsigned short* __restrict__ packed) {
    const int s = blockIdx.y, mat = blockIdx.z;
    const int t = blockIdx.x * 256 + threadIdx.x;
    const int lane = t & 63;
    int KS, width; size_t moff;
    if (mat == 0)      { KS = 4; width = 256; moff = 0; }
    else if (mat == 1) { KS = 4; width = 128; moff = 32768; }
    else if (mat == 2) { KS = 8; width = 128; moff = 49152; }
    else if (mat == 3) { KS = 8; width = 128; moff = 81920; }
    else               { KS = 8; width = 128; moff = 114688; }
    const int total = (width >> 4) * KS * 64;
    if (t >= total) return;
    const int ks = (t >> 6) % KS;
    const int ct = (t >> 6) / KS;
    const int col = ct * 16 + (lane & 15);
    const int kb = ks * 32 + (lane >> 4) * 8;
    unsigned short* dh = packed + (size_t)s * 294912 + moff;
    unsigned short* dl = dh + 147456;
#pragma unroll
    for (int j = 0; j < 8; ++j) {
        const int k = kb + j;
        float v;
        if (mat == 0) {
            const float* W = W_m1 + (size_t)s * 260 * 128;
            v = (col < 128) ? W[k * 128 + col] : W[(128 + k) * 128 + (col - 128)];
        } else if (mat == 1) {
            v = W_m2[(size_t)s * 16384 + k * 128 + col];
        } else if (mat == 2) {
            v = W_z[(size_t)s * 32768 + k * 128 + col];
        } else if (mat == 3) {
            v = W_r[(size_t)s * 32768 + k * 128 + col];
        } else {
            v = W_h[(size_t)s * 32768 + k * 128 + col];
        }
        unsigned int hb = f2bf(v);
        dh[(size_t)t * 8 + j] = (unsigned short)hb;
        dl[(size_t)t * 8 + j] = (unsigned short)f2bf(v - bf2f(hb));
    }
}

// ---------------- head weight packing: [Wc1|Wp1] as 128x128, hi+lo (16384 elems each) ----------------
__global__ __launch_bounds__(256) void pack_head_k(const float* __restrict__ Wc1,
                                                   const float* __restrict__ Wp1,
                                                   unsigned short* __restrict__ dst) {
    const int t = blockIdx.x * 256 + threadIdx.x;   // 0..2047
    if (t >= 2048) return;
    const int lane = t & 63;
    const int ks = (t >> 6) & 3;
    const int ct = (t >> 6) >> 2;
    const int col = ct * 16 + (lane & 15);
    const int kb = ks * 32 + (lane >> 4) * 8;
    unsigned short* dh = dst;
    unsigned short* dl = dst + 16384;
#pragma unroll
    for (int j = 0; j < 8; ++j) {
        const int k = kb + j;
        float v = (col < 64) ? Wc1[k * 64 + col] : Wp1[k * 64 + (col - 64)];
        unsigned int hb = f2bf(v);
        dh[(size_t)t * 8 + j] = (unsigned short)hb;
        dl[(size_t)t * 8 + j] = (unsigned short)f2bf(v - bf2f(hb));
    }
}

// ---------------- input projection -> f32 h ----------------
__global__ __launch_bounds__(256) void proj_k(const float* __restrict__ nf, const float* __restrict__ Win,
                                              const float* __restrict__ bin,
                                              float* __restrict__ hf, int N) {
    const int lane = threadIdx.x & 63, wave = threadIdx.x >> 6;
    const int i = blockIdx.x * 4 + wave;
    if (i >= N) return;
    const int c0 = lane * 2;
    float a0 = bin[c0], a1 = bin[c0 + 1];
#pragma unroll
    for (int q = 0; q < 8; ++q) {
        float x = nf[(size_t)i * 8 + q];
        a0 += x * Win[q * 128 + c0];
        a1 += x * Win[q * 128 + c0 + 1];
    }
    hf[(size_t)i * 128 + c0] = a0;
    hf[(size_t)i * 128 + c0 + 1] = a1;
}

// ---------------- f32-accurate MFMA GEMM, direct L2 weight reads, no barriers ----------------
// MODE 0: [Xs|Xd] = h@[W1s|W1d] : A=hf lda=128; cgrp0 -> Xs bf16 [N,128]; cgrp1 -> Xd f32 X[:,128:256]
// MODE 1: agg = T@W2 + deg*b : A=X+128 lda=256, out f32 X[:,0:128]
template <int MODE>
__global__ __launch_bounds__(256, 4) void gemm_k(const float* __restrict__ A, int lda,
                                                 const unsigned short* __restrict__ pkh,
                                                 const unsigned short* __restrict__ pkl,
                                                 const float* __restrict__ bias,
                                                 const int* __restrict__ deg,
                                                 float* __restrict__ out, int ldo,
                                                 unsigned short* __restrict__ out_b,
                                                 int Nrows) {
    const int lane = threadIdx.x & 63;
    const int wave = threadIdx.x >> 6;
    const int l15 = lane & 15, l16 = lane >> 4;
    const int mrow = blockIdx.x * 64 + wave * 16;
    const int cgrp = blockIdx.y;

    int r0 = mrow + l15; if (r0 >= Nrows) r0 = 0;
    const float* ap = A + (size_t)r0 * lda;

    f32x4 acc[8];
#pragma unroll
    for (int ct = 0; ct < 8; ++ct) acc[ct] = (f32x4){0.f, 0.f, 0.f, 0.f};

    for (int ks = 0; ks < 4; ++ks) {
        const f32x8 av = *(const f32x8*)(ap + ks * 32 + l16 * 8);
        short8 ahi, alo;
        decompv(av, ahi, alo);
#pragma unroll
        for (int ct = 0; ct < 8; ++ct) {
            const size_t fb = (((size_t)(cgrp * 8 + ct) * 4 + ks) << 10) + lane * 16;
            const short8 wh = *(const short8*)((const char*)pkh + fb);
            const short8 wl = *(const short8*)((const char*)pkl + fb);
            acc[ct] = __builtin_amdgcn_mfma_f32_16x16x32_bf16(ahi, wh, acc[ct], 0, 0, 0);
            acc[ct] = __builtin_amdgcn_mfma_f32_16x16x32_bf16(alo, wh, acc[ct], 0, 0, 0);
            acc[ct] = __builtin_amdgcn_mfma_f32_16x16x32_bf16(ahi, wl, acc[ct], 0, 0, 0);
        }
    }
#pragma unroll
    for (int ct = 0; ct < 8; ++ct) {
        const int col = cgrp * 128 + ct * 16 + l15;
#pragma unroll
        for (int r = 0; r < 4; ++r) {
            const int row = mrow + l16 * 4 + r;
            if (row >= Nrows) continue;
            float v = acc[ct][r];
            if (MODE == 0) {
                if (cgrp == 0) out_b[(size_t)row * 128 + col] = (unsigned short)f2bf(v);
                else           out[(size_t)row * ldo + col] = v;   // col in 128..255 -> Xd slot
            } else {
                v += bias[col] * (float)deg[row];
                out[(size_t)row * ldo + col] = v;
            }
        }
    }
}

// ---------------- fused z,r,rh,hn,blend,LN — 512 thr: 4 rowgrp x 2 colgrp, 16 rows x 64 cols/wave ----------------
__global__ __launch_bounds__(512, 4) void zrh_k(float* __restrict__ hf,
                                                const float* __restrict__ X,  // [N,256]: 0:128 agg
                                                const unsigned short* __restrict__ pzh, const unsigned short* __restrict__ pzl,
                                                const unsigned short* __restrict__ prh, const unsigned short* __restrict__ prl,
                                                const unsigned short* __restrict__ phh, const unsigned short* __restrict__ phl,
                                                const float* __restrict__ bz, const float* __restrict__ br,
                                                const float* __restrict__ bh,
                                                const float* __restrict__ lns, const float* __restrict__ lnb,
                                                int N) {
    __shared__ char stg[49152];   // phase1: 48 weight lines x 1KB; phase2+: rhs[4][2112] f32 + LN partials
    float* rhs = reinterpret_cast<float*>(stg);
    float* lnp = reinterpret_cast<float*>(stg + 33792);  // [4][2][16][2]
    const int lane = threadIdx.x & 63;
    const int wave = threadIdx.x >> 6;           // 0..7
    const int rowgrp = wave >> 1, colgrp = wave & 1;
    const int l15 = lane & 15, l16 = lane >> 4;
    const int mrow = blockIdx.x * 64 + rowgrp * 16;

    int r0 = mrow + l15; if (r0 >= N) r0 = 0;

    f32x4 zac[4], rac[4], hac[4];
#pragma unroll
    for (int c = 0; c < 4; ++c) {
        zac[c] = (f32x4){0.f, 0.f, 0.f, 0.f};
        rac[c] = (f32x4){0.f, 0.f, 0.f, 0.f};
        hac[c] = (f32x4){0.f, 0.f, 0.f, 0.f};
    }

    const unsigned short* wsrc[6] = {pzh, pzl, prh, prl, phh, phl};

    // ---- phase 1: staged weights, counted vmcnt, 2 barriers/ks ----
    f32x8 acur = *(const f32x8*)(hf + (size_t)r0 * 128 + l16 * 8);
    for (int ks = 0; ks < 8; ++ks) {
        const int nplanes = (ks >= 4) ? 6 : 4;
        for (int i = 0; i < nplanes; ++i)
            gl_lds16((const char*)wsrc[i] + (((size_t)(wave * 8 + ks)) << 10) + lane * 16,
                     &stg[(i * 8 + wave) << 10]);
        f32x8 anext;
        if (ks < 7) {
            const int kn = (ks + 1) * 32 + l16 * 8;
            const float* ap = (kn < 128) ? (hf + (size_t)r0 * 128 + kn)
                                         : (X + (size_t)r0 * 256 + (kn - 128));
            f32x4 pa = *(const f32x4*)ap;
            f32x4 pb = *(const f32x4*)(ap + 4);
            anext[0] = pa[0]; anext[1] = pa[1]; anext[2] = pa[2]; anext[3] = pa[3];
            anext[4] = pb[0]; anext[5] = pb[1]; anext[6] = pb[2]; anext[7] = pb[3];
        }
        short8 ahi, alo;
        decompv(acur, ahi, alo);
        if (ks < 7) asm volatile("s_waitcnt vmcnt(2)" ::: "memory");
        else        asm volatile("s_waitcnt vmcnt(0)" ::: "memory");
        __builtin_amdgcn_sched_barrier(0);
        __builtin_amdgcn_s_barrier();
        __builtin_amdgcn_sched_barrier(0);
#pragma unroll
        for (int c = 0; c < 4; ++c) {
            const int ct = colgrp * 4 + c;
            const short8 wzh = *(const short8*)(stg + ((0 * 8 + ct) << 10) + lane * 16);
            const short8 wzl = *(const short8*)(stg + ((1 * 8 + ct) << 10) + lane * 16);
            const short8 wrh = *(const short8*)(stg + ((2 * 8 + ct) << 10) + lane * 16);
            const short8 wrl = *(const short8*)(stg + ((3 * 8 + ct) << 10) + lane * 16);
            zac[c] = __builtin_amdgcn_mfma_f32_16x16x32_bf16(ahi, wzh, zac[c], 0, 0, 0);
            zac[c] = __builtin_amdgcn_mfma_f32_16x16x32_bf16(alo, wzh, zac[c], 0, 0, 0);
            zac[c] = __builtin_amdgcn_mfma_f32_16x16x32_bf16(ahi, wzl, zac[c], 0, 0, 0);
            rac[c] = __builtin_amdgcn_mfma_f32_16x16x32_bf16(ahi, wrh, rac[c], 0, 0, 0);
            rac[c] = __builtin_amdgcn_mfma_f32_16x16x32_bf16(alo, wrh, rac[c], 0, 0, 0);
            rac[c] = __builtin_amdgcn_mfma_f32_16x16x32_bf16(ahi, wrl, rac[c], 0, 0, 0);
            if (ks >= 4) {
                const short8 wbh = *(const short8*)(stg + ((4 * 8 + ct) << 10) + lane * 16);
                const short8 wbl = *(const short8*)(stg + ((5 * 8 + ct) << 10) + lane * 16);
                hac[c] = __builtin_amdgcn_mfma_f32_16x16x32_bf16(ahi, wbh, hac[c], 0, 0, 0);
                hac[c] = __builtin_amdgcn_mfma_f32_16x16x32_bf16(alo, wbh, hac[c], 0, 0, 0);
                hac[c] = __builtin_amdgcn_mfma_f32_16x16x32_bf16(ahi, wbl, hac[c], 0, 0, 0);
            }
        }
        __builtin_amdgcn_sched_barrier(0);
        __builtin_amdgcn_s_barrier();
        acur = anext;
    }

    // ---- phase 2: z = sigmoid (keep); rh = sigmoid(r)*h -> LDS rhs[rowgrp][rowl][col] ----
#pragma unroll
    for (int c = 0; c < 4; ++c) {
        const int col = (colgrp * 4 + c) * 16 + l15;
#pragma unroll
        for (int r = 0; r < 4; ++r) {
            const int rowl = l16 * 4 + r;
            const int row = mrow + rowl;
            const size_t idx = (size_t)(row < N ? row : 0) * 128 + col;
            float zp = zac[c][r] + bz[col];
            zac[c][r] = 1.f / (1.f + expf(-zp));
            float rp = rac[c][r] + br[col];
            float rr = 1.f / (1.f + expf(-rp));
            rhs[rowgrp * 2112 + rowl * 132 + col] = rr * hf[idx];
        }
    }
    __syncthreads();

    // ---- phase 3: hn += rh @ Wh_top (K=128), weights direct from L2 ----
    for (int ks = 0; ks < 4; ++ks) {
        const f32x8 v = *(const f32x8*)(rhs + rowgrp * 2112 + l15 * 132 + (ks * 4 + l16) * 8);
        short8 ahi, alo;
        decompv(v, ahi, alo);
#pragma unroll
        for (int c = 0; c < 4; ++c) {
            const int ct = colgrp * 4 + c;
            const size_t fb = (((size_t)(ct * 8 + ks)) << 10) + lane * 16;
            const short8 wh = *(const short8*)((const char*)phh + fb);
            const short8 wl = *(const short8*)((const char*)phl + fb);
            hac[c] = __builtin_amdgcn_mfma_f32_16x16x32_bf16(ahi, wh, hac[c], 0, 0, 0);
            hac[c] = __builtin_amdgcn_mfma_f32_16x16x32_bf16(alo, wh, hac[c], 0, 0, 0);
            hac[c] = __builtin_amdgcn_mfma_f32_16x16x32_bf16(ahi, wl, hac[c], 0, 0, 0);
        }
    }

    // ---- phase 4: blend + cross-wave LayerNorm -> hf ----
#pragma unroll
    for (int c = 0; c < 4; ++c) {
        const int col = (colgrp * 4 + c) * 16 + l15;
#pragma unroll
        for (int r = 0; r < 4; ++r) {
            const int row = mrow + l16 * 4 + r;
            const size_t idx = (size_t)(row < N ? row : 0) * 128 + col;
            float hn = tanhf(hac[c][r] + bh[col]);
            float zz = zac[c][r];
            hac[c][r] = (1.f - zz) * hf[idx] + zz * hn;
        }
    }
    float sr[4], ssr[4];
#pragma unroll
    for (int r = 0; r < 4; ++r) {
        float s = 0.f, ss = 0.f;
#pragma unroll
        for (int c = 0; c < 4; ++c) {
            float y = hac[c][r];
            s += y; ss += y * y;
        }
#pragma unroll
        for (int m = 1; m < 16; m <<= 1) {
            s += __shfl_xor(s, m, 64);
            ss += __shfl_xor(ss, m, 64);
        }
        sr[r] = s; ssr[r] = ss;
        if (l15 == 0) {
            float* p = lnp + (((rowgrp * 2 + colgrp) * 16) + (l16 * 4 + r)) * 2;
            p[0] = s; p[1] = ss;
        }
    }
    __syncthreads();
#pragma unroll
    for (int r = 0; r < 4; ++r) {
        const int rowl = l16 * 4 + r;
        const int row = mrow + rowl;
        const float* po = lnp + (((rowgrp * 2 + (colgrp ^ 1)) * 16) + rowl) * 2;
        float s = sr[r] + po[0];
        float ss = ssr[r] + po[1];
        float mean = s * (1.f / 128.f);
        float var = ss * (1.f / 128.f) - mean * mean;
        float inv = rsqrtf(var + 1e-6f);
        if (row < N) {
#pragma unroll
            for (int c = 0; c < 4; ++c) {
                const int col = (colgrp * 4 + c) * 16 + l15;
                hf[(size_t)row * 128 + col] = (hac[c][r] - mean) * inv * lns[col] + lnb[col];
            }
        }
    }
}

// ---------------- edge accumulate (unroll-4 MLP): T[v] = sum relu(Xs16[src]+Xd[v]+ef16@Wef+b1) ----------------
__global__ __launch_bounds__(256) void edge_k(float* __restrict__ X,
                                              const unsigned short* __restrict__ Xs16,
                                              const int* __restrict__ offs,
                                              const int* __restrict__ src_sorted,
                                              const uint2* __restrict__ ef16_sorted,
                                              const float* __restrict__ Wm1_s,
                                              const float* __restrict__ bm1_s,
                                              int N) {
    const int lane = threadIdx.x & 63, wave = threadIdx.x >> 6;
    const int v = blockIdx.x * 4 + wave;
    if (v >= N) return;
    const int c0 = lane * 2;
    const float base0 = X[(size_t)v * 256 + 128 + c0] + bm1_s[c0];
    const float base1 = X[(size_t)v * 256 + 129 + c0] + bm1_s[c0 + 1];
    const float w0x = Wm1_s[256 * 128 + c0], w0y = Wm1_s[256 * 128 + c0 + 1];
    const float w1x = Wm1_s[257 * 128 + c0], w1y = Wm1_s[257 * 128 + c0 + 1];
    const float w2x = Wm1_s[258 * 128 + c0], w2y = Wm1_s[258 * 128 + c0 + 1];
    const float w3x = Wm1_s[259 * 128 + c0], w3y = Wm1_s[259 * 128 + c0 + 1];
    float acc0 = 0.f, acc1 = 0.f;
    const int beg = offs[v], end = offs[v + 1];
    int i = beg;
    // unrolled-by-4: batch the index/feature loads, issue 4 independent row-gathers
    for (; i + 3 < end; i += 4) {
        int sn0 = src_sorted[i], sn1 = src_sorted[i + 1];
        int sn2 = src_sorted[i + 2], sn3 = src_sorted[i + 3];
        uint2 ep0 = ef16_sorted[i], ep1 = ef16_sorted[i + 1];
        uint2 ep2 = ef16_sorted[i + 2], ep3 = ef16_sorted[i + 3];
        unsigned int xs0 = *reinterpret_cast<const unsigned int*>(Xs16 + (size_t)sn0 * 128 + c0);
        unsigned int xs1 = *reinterpret_cast<const unsigned int*>(Xs16 + (size_t)sn1 * 128 + c0);
        unsigned int xs2 = *reinterpret_cast<const unsigned int*>(Xs16 + (size_t)sn2 * 128 + c0);
        unsigned int xs3 = *reinterpret_cast<const unsigned int*>(Xs16 + (size_t)sn3 * 128 + c0);
        {
            float efa = bf2f(ep0.x & 0xffffu), efb = bf2f(ep0.x >> 16);
            float efc = bf2f(ep0.y & 0xffffu), efd = bf2f(ep0.y >> 16);
            float e0 = efa * w0x + efb * w1x + efc * w2x + efd * w3x;
            float e1 = efa * w0y + efb * w1y + efc * w2y + efd * w3y;
            acc0 += fmaxf(bf2f(xs0 & 0xffffu) + base0 + e0, 0.f);
            acc1 += fmaxf(bf2f(xs0 >> 16) + base1 + e1, 0.f);
        }
        {
            float efa = bf2f(ep1.x & 0xffffu), efb = bf2f(ep1.x >> 16);
            float efc = bf2f(ep1.y & 0xffffu), efd = bf2f(ep1.y >> 16);
            float e0 = efa * w0x + efb * w1x + efc * w2x + efd * w3x;
            float e1 = efa * w0y + efb * w1y + efc * w2y + efd * w3y;
            acc0 += fmaxf(bf2f(xs1 & 0xffffu) + base0 + e0, 0.f);
            acc1 += fmaxf(bf2f(xs1 >> 16) + base1 + e1, 0.f);
        }
        {
            float efa = bf2f(ep2.x & 0xffffu), efb = bf2f(ep2.x >> 16);
            float efc = bf2f(ep2.y & 0xffffu), efd = bf2f(ep2.y >> 16);
            float e0 = efa * w0x + efb * w1x + efc * w2x + efd * w3x;
            float e1 = efa * w0y + efb * w1y + efc * w2y + efd * w3y;
            acc0 += fmaxf(bf2f(xs2 & 0xffffu) + base0 + e0, 0.f);
            acc1 += fmaxf(bf2f(xs2 >> 16) + base1 + e1, 0.f);
        }
        {
            float efa = bf2f(ep3.x & 0xffffu), efb = bf2f(ep3.x >> 16);
            float efc = bf2f(ep3.y & 0xffffu), efd = bf2f(ep3.y >> 16);
            float e0 = efa * w0x + efb * w1x + efc * w2x + efd * w3x;
            float e1 = efa * w0y + efb * w1y + efc * w2y + efd * w3y;
            acc0 += fmaxf(bf2f(xs3 & 0xffffu) + base0 + e0, 0.f);
            acc1 += fmaxf(bf2f(xs3 >> 16) + base1 + e1, 0.f);
        }
    }
    for (; i < end; ++i) {
        int sn = src_sorted[i];
        uint2 efp = ef16_sorted[i];
        float efa = bf2f(efp.x & 0xffffu), efb = bf2f(efp.x >> 16);
        float efc = bf2f(efp.y & 0xffffu), efd = bf2f(efp.y >> 16);
        unsigned int xs = *reinterpret_cast<const unsigned int*>(Xs16 + (size_t)sn * 128 + c0);
        float e0 = efa * w0x + efb * w1x + efc * w2x + efd * w3x;
        float e1 = efa * w0y + efb * w1y + efc * w2y + efd * w3y;
        acc0 += fmaxf(bf2f(xs & 0xffffu) + base0 + e0, 0.f);
        acc1 += fmaxf(bf2f(xs >> 16) + base1 + e1, 0.f);
    }
    X[(size_t)v * 256 + 128 + c0] = acc0;   // T overwrites Xd (consumed above)
    X[(size_t)v * 256 + 129 + c0] = acc1;
}

// ---------------- heads: MFMA stage-1 (h@[Wc1|Wp1]) + LDS stage-2 ----------------
__global__ __launch_bounds__(256, 4) void head_k(const float* __restrict__ hf,
                                                 const unsigned short* __restrict__ pH,  // hi; lo at +16384
                                                 const float* __restrict__ bc1, const float* __restrict__ bp1,
                                                 const float* __restrict__ Wc2, const float* __restrict__ bc2,
                                                 const float* __restrict__ Wp2, const float* __restrict__ bp2,
                                                 float* __restrict__ out, int N) {
    __shared__ float tls[4][16][132];
    const int lane = threadIdx.x & 63, wave = threadIdx.x >> 6;
    const int l15 = lane & 15, l16 = lane >> 4;
    const int mrow = blockIdx.x * 64 + wave * 16;
    const unsigned short* pHl = pH + 16384;

    int r0 = mrow + l15; if (r0 >= N) r0 = 0;
    const float* ap = hf + (size_t)r0 * 128;

    f32x4 acc[8];
#pragma unroll
    for (int ct = 0; ct < 8; ++ct) acc[ct] = (f32x4){0.f, 0.f, 0.f, 0.f};

    for (int ks = 0; ks < 4; ++ks) {
        const f32x8 av = *(const f32x8*)(ap + ks * 32 + l16 * 8);
        short8 ahi, alo;
        decompv(av, ahi, alo);
#pragma unroll
        for (int ct = 0; ct < 8; ++ct) {
            const size_t fb = (((size_t)(ct * 4 + ks)) << 10) + lane * 16;
            const short8 wh = *(const short8*)((const char*)pH + fb);
            const short8 wl = *(const short8*)((const char*)pHl + fb);
            acc[ct] = __builtin_amdgcn_mfma_f32_16x16x32_bf16(ahi, wh, acc[ct], 0, 0, 0);
            acc[ct] = __builtin_amdgcn_mfma_f32_16x16x32_bf16(alo, wh, acc[ct], 0, 0, 0);
            acc[ct] = __builtin_amdgcn_mfma_f32_16x16x32_bf16(ahi, wl, acc[ct], 0, 0, 0);
        }
    }
    // relu + bias -> per-wave LDS tile (cols 0:64 = cls-hidden, 64:128 = prob-hidden)
#pragma unroll
    for (int ct = 0; ct < 8; ++ct) {
        const int col = ct * 16 + l15;
        const float b = (col < 64) ? bc1[col] : bp1[col - 64];
#pragma unroll
        for (int r = 0; r < 4; ++r) {
            const int rowl = l16 * 4 + r;
            tls[wave][rowl][col] = fmaxf(acc[ct][r] + b, 0.f);
        }
    }
    // stage 2: 4-lane groups per row
    const int rowl = lane & 15;
    const int g = lane >> 4;
    const int row = mrow + rowl;
    const float* tr = &tls[wave][rowl][0];
    float o0 = 0.f, o1 = 0.f;
    if (g == 0) {
        for (int k = 0; k < 64; ++k) { float tv = tr[k]; o0 += tv * Wc2[k * 5 + 0]; o1 += tv * Wc2[k * 5 + 4]; }
    } else if (g == 1) {
        for (int k = 0; k < 64; ++k) { o0 += tr[k] * Wc2[k * 5 + 1]; o1 += tr[64 + k] * Wp2[k]; }
    } else if (g == 2) {
        for (int k = 0; k < 64; ++k) o0 += tr[k] * Wc2[k * 5 + 2];
    } else {
        for (int k = 0; k < 64; ++k) o0 += tr[k] * Wc2[k * 5 + 3];
    }
    if (row < N) {
        if (g == 0) {
            out[(size_t)row * 5 + 0] = o0 + bc2[0];
            out[(size_t)row * 5 + 4] = o1 + bc2[4];
        } else if (g == 1) {
            out[(size_t)row * 5 + 1] = o0 + bc2[1];
            out[(size_t)N * 5 + row] = 1.f / (1.f + expf(-(o1 + bp2[0])));
        } else if (g == 2) {
            out[(size_t)row * 5 + 2] = o0 + bc2[2];
        } else {
            out[(size_t)row * 5 + 3] = o0 + bc2[3];
        }
    }
}

extern "C" void kernel_launch(void* const* d_in, const int* in_sizes, int n_in,
                              void* d_out, int out_size, void* d_ws, size_t ws_size,
                              hipStream_t stream) {
    const float* node_feats = (const float*)d_in[0];
    const int*   edge_index = (const int*)d_in[1];
    const float* edge_feats = (const float*)d_in[2];
    const float* W_in = (const float*)d_in[3];
    const float* b_in = (const float*)d_in[4];
    const float* W_m1 = (const float*)d_in[5];
    const float* b_m1 = (const float*)d_in[6];
    const float* W_m2 = (const float*)d_in[7];
    const float* b_m2 = (const float*)d_in[8];
    const float* W_z  = (const float*)d_in[9];
    const float* b_z  = (const float*)d_in[10];
    const float* W_r  = (const float*)d_in[11];
    const float* b_r  = (const float*)d_in[12];
    const float* W_h  = (const float*)d_in[13];
    const float* b_h  = (const float*)d_in[14];
    const float* ln_s = (const float*)d_in[15];
    const float* ln_b = (const float*)d_in[16];
    const float* W_c1 = (const float*)d_in[17];
    const float* b_c1 = (const float*)d_in[18];
    const float* W_c2 = (const float*)d_in[19];
    const float* b_c2 = (const float*)d_in[20];
    const float* W_p1 = (const float*)d_in[21];
    const float* b_p1 = (const float*)d_in[22];
    const float* W_p2 = (const float*)d_in[23];
    const float* b_p2 = (const float*)d_in[24];

    const int N = in_sizes[0] / 8;
    const int E = in_sizes[2] / 4;

    char* ws = (char*)d_ws;
    size_t off = 0;
    auto alloc = [&](size_t bytes) { size_t p = off; off = (off + bytes + 255) & ~(size_t)255; return p; };
    const size_t o_hf = alloc((size_t)N * 128 * 4);   // f32 h
    const size_t o_X  = alloc((size_t)N * 256 * 4);   // f32 [agg|Xd->T]
    const size_t o_xs = alloc((size_t)N * 128 * 2);   // bf16 Xs gather table
    const size_t o_pk = alloc(((size_t)STEPS * 294912 + 32768) * 2);
    const size_t o_deg = alloc((size_t)N * 4);
    const size_t o_off = alloc((size_t)(N + 1) * 4);
    const size_t o_cur = alloc((size_t)N * 4);
    const size_t o_ex  = alloc((size_t)N * 4);
    const size_t o_bs  = alloc(1024 * 4);
    const size_t o_be  = alloc(1024 * 4);
    const size_t o_ss  = alloc((size_t)E * 4);   // src_sorted
    const size_t o_ef  = alloc((size_t)E * 8);   // ef16_sorted (4x bf16)

    if (off > ws_size) {  // fail cleanly (diagnosable) instead of faulting
        hipMemsetAsync(d_out, 0, (size_t)out_size * 4, stream);
        return;
    }

    float* hf = (float*)(ws + o_hf);
    float* X  = (float*)(ws + o_X);
    unsigned short* Xs16 = (unsigned short*)(ws + o_xs);
    unsigned short* pH = (unsigned short*)(ws + o_pk) + (size_t)STEPS * 294912;

    // ---- CSR by dst ----
    hipMemsetAsync(ws + o_deg, 0, (size_t)N * 4, stream);
    hipMemsetAsync(ws + o_cur, 0, (size_t)N * 4, stream);
    hist_k<<<(E + 255) / 256, 256, 0, stream>>>(edge_index + E, (int*)(ws + o_deg), E);
    const int nb1 = (N + 1023) / 1024;
    scan1_k<<<nb1, 256, 0, stream>>>((int*)(ws + o_deg), (int*)(ws + o_ex), (int*)(ws + o_bs), N);
    scan2_k<<<1, 1024, 0, stream>>>((int*)(ws + o_bs), (int*)(ws + o_be), nb1);
    scan3_k<<<(N + 1 + 255) / 256, 256, 0, stream>>>((int*)(ws + o_ex), (int*)(ws + o_be),
                                                     (int*)(ws + o_off), N, E);
    scatter_k<<<(E + 255) / 256, 256, 0, stream>>>(edge_index, edge_index + E,
                                                   (const float4*)edge_feats, (int*)(ws + o_off),
                                                   (int*)(ws + o_cur), (int*)(ws + o_ss),
                                                   (uint2*)(ws + o_ef), E);
    // ---- pack weights (hi+lo planes) ----
    pack_k<<<dim3(16, STEPS, 5), 256, 0, stream>>>(W_m1, W_m2, W_z, W_r, W_h,
                                                   (unsigned short*)(ws + o_pk));
    pack_head_k<<<8, 256, 0, stream>>>(W_c1, W_p1, pH);
    // ---- input projection (f32) ----
    proj_k<<<(N + 3) / 4, 256, 0, stream>>>(node_feats, W_in, b_in, hf, N);

    const int MB2 = (N + 63) / 64;

    for (int s = 0; s < STEPS; ++s) {
        const unsigned short* pk = (const unsigned short*)(ws + o_pk) + (size_t)s * 294912;
        const unsigned short* pkL = pk + 147456;
        // Xs (bf16) | Xd (f32) = h@[W1s|W1d]
        gemm_k<0><<<dim3(MB2, 2), 256, 0, stream>>>(hf, 128, pk, pkL, nullptr, nullptr,
                                                    X, 256, Xs16, N);
        // T[v] = sum relu(Xs16[src] + Xd + ef16@Wef + b1) -> X[:,128:256]
        edge_k<<<(N + 3) / 4, 256, 0, stream>>>(X, Xs16, (int*)(ws + o_off), (int*)(ws + o_ss),
                                                (const uint2*)(ws + o_ef),
                                                W_m1 + (size_t)s * 33280, b_m1 + (size_t)s * 128, N);
        // agg = T@W2 + deg*b_m2 -> X[:,0:128]
        gemm_k<1><<<dim3(MB2, 1), 256, 0, stream>>>(X + 128, 256, pk + 32768, pkL + 32768,
                                                    b_m2 + (size_t)s * 128, (int*)(ws + o_deg),
                                                    X, 256, nullptr, N);
        // fused gates + candidate + blend + LN (in-place hf; rh via LDS)
        zrh_k<<<MB2, 512, 0, stream>>>(hf, X,
                                       pk + 49152, pkL + 49152,     // Wz hi/lo
                                       pk + 81920, pkL + 81920,     // Wr hi/lo
                                       pk + 114688, pkL + 114688,   // Wh hi/lo
                                       b_z + (size_t)s * 128, b_r + (size_t)s * 128,
                                       b_h + (size_t)s * 128,
                                       ln_s + (size_t)s * 128, ln_b + (size_t)s * 128, N);
    }

    head_k<<<MB2, 256, 0, stream>>>(hf, pH, b_c1, b_p1, W_c2, b_c2, W_p2, b_p2,
                                    (float*)d_out, N);
}